// Round 7
// baseline (271.544 us; speedup 1.0000x reference)
//
#include <hip/hip_runtime.h>
#include <hip/hip_bf16.h>
#include <cstdint>
#include <cstddef>

// ButterflyLayer2D on MI355X.
// k_s01 = fused patch-embed + level-1 (computes x0 inline per L1 position,
// 4 children share A via wave=child) -> levels 2-3 as bf16 MFMA GEMMs
// (4-children A-sharing) -> k_f456 = fused L4+L5+L6+final.
// Weights pre-transposed once into MFMA B-fragment layout (bf16) in d_ws.

typedef __attribute__((ext_vector_type(8))) short short8;
typedef __attribute__((ext_vector_type(4))) float f32x4;
typedef unsigned short ushort_t;

static __device__ __forceinline__ float b2f(const __hip_bfloat16 x) {
    return __bfloat162float(x);
}
static __device__ __forceinline__ ushort_t f2bf(float x) {
    __hip_bfloat16 h = __float2bfloat16(x);
    ushort_t u;
    __builtin_memcpy(&u, &h, 2);
    return u;
}
static __device__ __forceinline__ void gl_lds16(const void* g, void* l) {
    __builtin_amdgcn_global_load_lds(
        (const __attribute__((address_space(1))) void*)g,
        (__attribute__((address_space(3))) void*)l, 16, 0, 0);
}
// gfx9 waitcnt encodings: lgkmcnt(0) only / vmcnt(0) only
#define WAIT_LGKM0() __builtin_amdgcn_s_waitcnt(0xC07F)
#define WAIT_VM0()   __builtin_amdgcn_s_waitcnt(0x0F70)

// ---------------------------------------------------------------------------
// k_prep: merged dtype-detect + weight transpose + bias convert (verified r6).
// gid ranges: [0,565248) level weights; [565248,630784) Wd; [630784,648448) bias.
// ---------------------------------------------------------------------------
__global__ __launch_bounds__(256) void k_prep(
    const uint32_t* __restrict__ in_words,
    const void* f1, const void* f2, const void* f3,
    const void* f4, const void* f5, const void* f6, const void* wdsrc,
    const void* b1, const void* b2, const void* b3,
    const void* b4, const void* b5, const void* b6,
    ushort_t* __restrict__ wbuf, ushort_t* __restrict__ wdbuf,
    float* __restrict__ bbuf, int* __restrict__ flag)
{
    __shared__ int sflag;
    const int t = threadIdx.x;
    if (t < 64) {
        const float v = __uint_as_float(in_words[t]);
        const bool plaus = (v == 0.0f) || (fabsf(v) > 1e-8f && fabsf(v) < 1e4f);
        const unsigned long long m = __ballot(plaus);
        if (t == 0) sflag = (__popcll(m) >= 48) ? 0 : 1;
    }
    __syncthreads();
    const int isbf = sflag;
    const int gid = blockIdx.x * 256 + t;
    if (blockIdx.x == 0 && t == 0) *flag = isbf;

    if (gid >= 648448) return;
    if (gid >= 630784) {
        const int bg = gid - 630784;
        const void* src; int base;
        if      (bg <   256) { src = b1; base = 0;     }
        else if (bg <  1280) { src = b2; base = 256;   }
        else if (bg <  5376) { src = b3; base = 1280;  }
        else if (bg <  9472) { src = b4; base = 5376;  }
        else if (bg < 13568) { src = b5; base = 9472;  }
        else                 { src = b6; base = 13568; }
        const int local = bg - base;
        bbuf[bg] = isbf ? b2f(((const __hip_bfloat16*)src)[local])
                        : ((const float*)src)[local];
        return;
    }
    if (gid >= 565248) {
        const int local = gid - 565248;
        const int lane = local & 63;
        const int slot = (local >> 6) & 15;
        const int site = local >> 10;
        const int ks2 = slot >> 3, nh = slot & 7, q = lane >> 4;
        const int n = nh * 16 + (lane & 15);
        const int r = n >> 6, kk = n & 63;
        const int cbase = ks2 * 32 + q * 8;
        ushort_t pk[8];
        if (isbf) {
            const ushort_t* s = (const ushort_t*)wdsrc;
            #pragma unroll
            for (int j = 0; j < 8; j++)
                pk[j] = s[(((size_t)(site * 2 + r) * 64 + cbase + j) * 64) + kk];
        } else {
            const float* s = (const float*)wdsrc;
            #pragma unroll
            for (int j = 0; j < 8; j++)
                pk[j] = f2bf(s[(((size_t)(site * 2 + r) * 64 + cbase + j) * 64) + kk]);
        }
        *(uint4*)&wdbuf[(size_t)local * 8] = *(uint4*)pk;
        return;
    }
    const void* fsrc; int base;
    if      (gid <   8192) { fsrc = f1; base = 0;      }
    else if (gid <  40960) { fsrc = f2; base = 8192;   }
    else if (gid < 172032) { fsrc = f3; base = 40960;  }
    else if (gid < 303104) { fsrc = f4; base = 172032; }
    else if (gid < 434176) { fsrc = f5; base = 303104; }
    else                   { fsrc = f6; base = 434176; }
    const int local = gid - base;
    const int lane = local & 63;
    const int slot = (local >> 6) & 7;
    const int sitetap = local >> 9;
    const int ks = slot >> 2, nh = slot & 3, q = lane >> 4;
    const int n = (lane & 15) + nh * 16;
    const int kbase = ks * 32 + q * 8;
    ushort_t pk[8];
    if (isbf) {
        const ushort_t* s = (const ushort_t*)fsrc + (size_t)sitetap * 4096;
        #pragma unroll
        for (int j = 0; j < 8; j++) pk[j] = s[(kbase + j) * 64 + n];
    } else {
        const float* s = (const float*)fsrc + (size_t)sitetap * 4096;
        #pragma unroll
        for (int j = 0; j < 8; j++) pk[j] = f2bf(s[(kbase + j) * 64 + n]);
    }
    *(uint4*)&wbuf[(size_t)gid * 8] = *(uint4*)pk;
}

// ---------------------------------------------------------------------------
// k_s01: fused patch-embed + level 1.
// Block = (L1 position (h,w) in 32x32, 32-batch mtile). Waves = 4 children.
//  1. stage 8x8 f32 input patch per batch row (rows 8h..8h+7, cols 8w..8w+7)
//  2. VALU patch-embed: thread=(b, c-octet), 512 FMA -> bf16 A-frags (4 taps)
//  3. per tap: stage own child's B (wave-private, waitcnt only), 16 MFMA
//  4. per-wave epilogue: bias1+relu -> bf16 -> L1-out
// ---------------------------------------------------------------------------
__global__ __launch_bounds__(256, 2) void k_s01(
    const void* __restrict__ in_data,   // (128,256,256,1)
    const void* __restrict__ filt,      // (4,4,1,64)
    const void* __restrict__ bias0,     // (64)
    const ushort_t* __restrict__ w1,    // wbuf + L1 offset (site=child, 4*4096)
    const float* __restrict__ b1,       // bbuf + L1 offset
    __hip_bfloat16* __restrict__ xout,  // (4, Bc, 32,32,64)
    const int* __restrict__ flag, int Bc, int b_off, int mtiles)
{
    const int isbf = *flag;
    int idx = blockIdx.x;
    const int mt = idx % mtiles; idx /= mtiles;
    const int w = idx & 31;
    const int h = idx >> 5;

    __shared__ float sIn[32][64];          // [b][p*8+q]
    __shared__ float sF[16][64];
    __shared__ float sB0[64];
    __shared__ float sBias[4][64];
    __shared__ ushort_t sA[4 * 4 * 512];   // [tap][slot(ks*2+mh)][lane*8]
    __shared__ ushort_t sB[4 * 8 * 512];   // [child][slot][lane*8], per tap

    const int t = threadIdx.x;
    const int wave = t >> 6, lane = t & 63;
    const int lm = lane & 15, lq = lane >> 4;

    // small tables
    if (isbf) {
        const __hip_bfloat16* fsrc = (const __hip_bfloat16*)filt;
        #pragma unroll
        for (int i = 0; i < 4; i++) {
            int flat = i * 256 + t;
            sF[flat >> 6][flat & 63] = b2f(fsrc[flat]);
        }
        if (t < 64) sB0[t] = b2f(((const __hip_bfloat16*)bias0)[t]);
    } else {
        const float* fsrc = (const float*)filt;
        #pragma unroll
        for (int i = 0; i < 4; i++) {
            int flat = i * 256 + t;
            sF[flat >> 6][flat & 63] = fsrc[flat];
        }
        if (t < 64) sB0[t] = ((const float*)bias0)[t];
    }
    sBias[t >> 6][t & 63] = b1[(t >> 6) * 64 + (t & 63)];

    // 1. stage input patch
    #pragma unroll
    for (int i = 0; i < 2; i++) {
        const int task = i * 256 + t;        // 512 float4 tasks
        const int half = task & 1, r = (task >> 1) & 7, b = task >> 4;
        int bl = mt * 32 + b;
        if (bl >= Bc) bl = Bc - 1;
        const size_t off = ((size_t)(b_off + bl) * 256 + 8 * h + r) * 256
                         + 8 * w + half * 4;
        float4 val;
        if (isbf) {
            const __hip_bfloat16* s = (const __hip_bfloat16*)in_data + off;
            val.x = b2f(s[0]); val.y = b2f(s[1]); val.z = b2f(s[2]); val.w = b2f(s[3]);
        } else {
            val = *(const float4*)((const float*)in_data + off);
        }
        *(float4*)&sIn[b][r * 8 + half * 4] = val;
    }
    __syncthreads();

    // 2. VALU patch-embed: thread = (vb, oct); 4 taps x 8 ch x 16 MAC
    {
        const int vb = t >> 3, oct = t & 7;
        float4 pf[16][2];
        #pragma unroll
        for (int pq = 0; pq < 16; pq++) {
            pf[pq][0] = *(const float4*)&sF[pq][oct * 8];
            pf[pq][1] = *(const float4*)&sF[pq][oct * 8 + 4];
        }
        const int ks = oct >> 2;
        const int slot = ks * 2 + (vb >> 4);
        const int ln = (vb & 15) | ((oct & 3) << 4);
        #pragma unroll
        for (int tap = 0; tap < 4; tap++) {
            const int x = tap >> 1, y = tap & 1;
            float4 rin[4];
            #pragma unroll
            for (int p = 0; p < 4; p++)
                rin[p] = *(const float4*)&sIn[vb][(4 * x + p) * 8 + 4 * y];
            float acc8[8];
            #pragma unroll
            for (int j = 0; j < 8; j++) acc8[j] = sB0[oct * 8 + j];
            #pragma unroll
            for (int p = 0; p < 4; p++) {
                #pragma unroll
                for (int q = 0; q < 4; q++) {
                    const float a = ((const float*)&rin[p])[q];
                    const float* fp = (const float*)&pf[p * 4 + q][0];
                    #pragma unroll
                    for (int j = 0; j < 8; j++)
                        acc8[j] = fmaf(a, fp[j], acc8[j]);
                }
            }
            ushort_t pk[8];
            #pragma unroll
            for (int j = 0; j < 8; j++) pk[j] = f2bf(fmaxf(acc8[j], 0.f));
            *(uint4*)&sA[((tap * 4 + slot) * 64 + ln) * 8] = *(uint4*)pk;
        }
    }
    __syncthreads();

    // 3. MFMA: per tap, wave stages own child's B (wave-private region)
    const f32x4 zero = {0.f, 0.f, 0.f, 0.f};
    f32x4 accm[2][4];
    #pragma unroll
    for (int i = 0; i < 2; i++)
        #pragma unroll
        for (int j = 0; j < 4; j++) accm[i][j] = zero;

    const ushort_t* wsite = w1 + (size_t)wave * 4 * 4096;   // so == wave
    for (int tap = 0; tap < 4; tap++) {
        WAIT_LGKM0();   // WAR: prior tap's ds_reads of own sB region done
        const ushort_t* wt = wsite + (size_t)tap * 4096;
        #pragma unroll
        for (int s = 0; s < 8; s++)
            gl_lds16(wt + s * 512 + lane * 8, &sB[wave * 4096 + s * 512]);
        WAIT_VM0();     // staged B visible (wave-private)
        #pragma unroll
        for (int ks = 0; ks < 2; ks++) {
            #pragma unroll
            for (int fm = 0; fm < 2; fm++) {
                short8 a = *(const short8*)&sA[((tap * 4 + ks * 2 + fm) * 64 + lane) * 8];
                #pragma unroll
                for (int fn = 0; fn < 4; fn++) {
                    short8 bfr = *(const short8*)&sB[wave * 4096 + (ks * 4 + fn) * 512 + lane * 8];
                    accm[fm][fn] = __builtin_amdgcn_mfma_f32_16x16x32_bf16(a, bfr, accm[fm][fn], 0, 0, 0);
                }
            }
        }
    }

    // 4. epilogue (own sB region; no cross-wave hazard)
    WAIT_LGKM0();
    {
        float bv[4];
        #pragma unroll
        for (int fn = 0; fn < 4; fn++) bv[fn] = sBias[wave][fn * 16 + lm];
        ushort_t* ob = &sB[wave * 4096];
        #pragma unroll
        for (int fm = 0; fm < 2; fm++) {
            #pragma unroll
            for (int fn = 0; fn < 4; fn++) {
                #pragma unroll
                for (int r = 0; r < 4; r++) {
                    const int row = fm * 16 + lq * 4 + r;
                    ob[row * 68 + fn * 16 + lm] =
                        f2bf(fmaxf(accm[fm][fn][r] + bv[fn], 0.f));
                }
            }
        }
        const size_t ostride = (size_t)32 * 32 * 64;
        const size_t obase = (size_t)wave * Bc * ostride + ((size_t)h * 32 + w) * 64;
        #pragma unroll
        for (int i = 0; i < 4; i++) {
            const int task = i * 64 + lane;
            const int oc = task & 7, row = task >> 3;
            const int b = mt * 32 + row;
            if (b < Bc) {
                *(uint4*)(xout + obase + (size_t)b * ostride + oc * 8) =
                    *(const uint4*)&ob[row * 68 + oc * 8];
            }
        }
    }
}

// ---------------------------------------------------------------------------
// Repeat level (2-3), verified rounds 4-6: block = (parent site, h, w, mtile
// of 64), wave = child; A fetched once for the 4 children.
// ---------------------------------------------------------------------------
__global__ __launch_bounds__(256) void k_level4(
    const __hip_bfloat16* __restrict__ xin,
    const ushort_t* __restrict__ wbuf,
    const float* __restrict__ bbuf,
    __hip_bfloat16* __restrict__ xout,
    int Nv_out, int HW, int Bc, int mtiles)
{
    __shared__ ushort_t smem[20480];
    __shared__ float sBias[4][64];
    ushort_t* sA = smem;
    ushort_t* sB = smem + 4096;

    int idx = blockIdx.x;
    const int mt = idx % mtiles; idx /= mtiles;
    const int w  = idx % HW; idx /= HW;
    const int h  = idx % HW; idx /= HW;
    const int Nv_in = Nv_out >> 1;
    const int vp = idx % Nv_in;
    const int up = idx / Nv_in;

    const int t = threadIdx.x;
    const int wave = t >> 6, lane = t & 63;
    const int lm = lane & 15, lq = lane >> 4;

    {
        const int ct = t >> 6, o = t & 63;
        const int so_t = (2 * up + (ct >> 1)) * Nv_out + (2 * vp + (ct & 1));
        sBias[ct][o] = bbuf[so_t * 64 + o];
    }

    const int so = (2 * up + (wave >> 1)) * Nv_out + (2 * vp + (wave & 1));
    const int H_in = HW * 2;
    const size_t bstride = (size_t)H_in * H_in * 64;
    const size_t siteb = (size_t)(up * Nv_in + vp) * Bc * bstride;
    const ushort_t* wsite = wbuf + (size_t)so * 4 * 4096;

    const f32x4 zero = {0.f, 0.f, 0.f, 0.f};
    f32x4 acc[4][4];
    #pragma unroll
    for (int i = 0; i < 4; i++)
        #pragma unroll
        for (int j = 0; j < 4; j++) acc[i][j] = zero;

    for (int tap = 0; tap < 4; tap++) {
        const int hi = 2 * h + (tap >> 1), wi = 2 * w + (tap & 1);
        const size_t tapoff = siteb + ((size_t)hi * H_in + wi) * 64;
        #pragma unroll
        for (int s2 = 0; s2 < 2; s2++) {
            const int s = wave * 2 + s2;
            const int ks = s >> 2, mh = s & 3;
            int b = mt * 64 + lm + mh * 16;
            if (b >= Bc) b = Bc - 1;
            gl_lds16(xin + tapoff + (size_t)b * bstride + ks * 32 + lq * 8,
                     &sA[s * 512]);
        }
        const ushort_t* wt = wsite + (size_t)tap * 4096;
        #pragma unroll
        for (int s = 0; s < 8; s++) {
            gl_lds16(wt + s * 512 + lane * 8, &sB[wave * 4096 + s * 512]);
        }
        __syncthreads();

        #pragma unroll
        for (int ks = 0; ks < 2; ks++) {
            short8 bf0 = *(const short8*)&sB[wave * 4096 + (ks * 4 + 0) * 512 + lane * 8];
            short8 bf1 = *(const short8*)&sB[wave * 4096 + (ks * 4 + 1) * 512 + lane * 8];
            short8 bf2 = *(const short8*)&sB[wave * 4096 + (ks * 4 + 2) * 512 + lane * 8];
            short8 bf3 = *(const short8*)&sB[wave * 4096 + (ks * 4 + 3) * 512 + lane * 8];
            #pragma unroll
            for (int fm = 0; fm < 4; fm++) {
                short8 a = *(const short8*)&sA[(ks * 4 + fm) * 512 + lane * 8];
                acc[fm][0] = __builtin_amdgcn_mfma_f32_16x16x32_bf16(a, bf0, acc[fm][0], 0, 0, 0);
                acc[fm][1] = __builtin_amdgcn_mfma_f32_16x16x32_bf16(a, bf1, acc[fm][1], 0, 0, 0);
                acc[fm][2] = __builtin_amdgcn_mfma_f32_16x16x32_bf16(a, bf2, acc[fm][2], 0, 0, 0);
                acc[fm][3] = __builtin_amdgcn_mfma_f32_16x16x32_bf16(a, bf3, acc[fm][3], 0, 0, 0);
            }
        }
        __syncthreads();
    }

    float bv[4];
    #pragma unroll
    for (int fn = 0; fn < 4; fn++) bv[fn] = sBias[wave][fn * 16 + lm];
    ushort_t* so_buf = smem + wave * 4352;
    #pragma unroll
    for (int fm = 0; fm < 4; fm++) {
        #pragma unroll
        for (int fn = 0; fn < 4; fn++) {
            #pragma unroll
            for (int r = 0; r < 4; r++) {
                const int row = fm * 16 + lq * 4 + r;
                so_buf[row * 68 + fn * 16 + lm] =
                    f2bf(fmaxf(acc[fm][fn][r] + bv[fn], 0.f));
            }
        }
    }
    __syncthreads();

    const size_t ostride = (size_t)HW * HW * 64;
    const size_t obase = (size_t)so * Bc * ostride + ((size_t)h * HW + w) * 64;
    #pragma unroll
    for (int i = 0; i < 8; i++) {
        const int task = i * 64 + lane;
        const int oct = task & 7, row = task >> 3;
        const int b = mt * 64 + row;
        if (b < Bc) {
            *(uint4*)(xout + obase + (size_t)b * ostride + oct * 8) =
                *(const uint4*)&so_buf[row * 68 + oct * 8];
        }
    }
}

// ---------------------------------------------------------------------------
// k_f456: fused L4 + L5 + L6 + final (verified round 6).
// ---------------------------------------------------------------------------
__global__ __launch_bounds__(256, 1) void k_f456(
    const __hip_bfloat16* __restrict__ xin,   // L3 out: (64, Bc, 8,8,64)
    const ushort_t* __restrict__ w4, const ushort_t* __restrict__ w5,
    const ushort_t* __restrict__ w6, const ushort_t* __restrict__ wd,
    const float* __restrict__ b4, const float* __restrict__ b5,
    const float* __restrict__ b6,
    void* __restrict__ out, const int* __restrict__ flag,
    int Bc, int b_off, int mtiles)
{
    const int isbf = *flag;
    const int bx = blockIdx.x;
    const int mt = bx % mtiles;
    const int site = bx / mtiles;
    const int u = site >> 3, v = site & 7;

    __shared__ ushort_t smem[74752];
    __shared__ float sBias[192];

    const int t = threadIdx.x;
    const int wv = t >> 6, lane = t & 63;
    const int lm = lane & 15, lq = lane >> 4;

    if (t < 64) {
        sBias[t]       = b4[site * 64 + t];
        sBias[64 + t]  = b5[site * 64 + t];
        sBias[128 + t] = b6[site * 64 + t];
    }

    {
        const ushort_t* w4s = w4 + (size_t)site * 16384;
        const ushort_t* w5s = w5 + (size_t)site * 16384;
        #pragma unroll
        for (int s2 = 0; s2 < 8; s2++) {
            const int s = wv * 8 + s2;
            gl_lds16(w4s + s * 512 + lane * 8, &smem[s * 512]);
            gl_lds16(w5s + s * 512 + lane * 8, &smem[16384 + s * 512]);
        }
    }
    __syncthreads();

    const f32x4 zero = {0.f, 0.f, 0.f, 0.f};
    const int h5 = wv >> 1, w5p = wv & 1;
    ushort_t* mid1w = smem + 32768 + wv * 8448;
    ushort_t* Aw = smem + 66560 + wv * 2048;
    const size_t sb = (size_t)site * Bc;

    // phase 1: L4
    for (int i = 0; i < 4; i++) {
        const int h4 = 2 * h5 + (i >> 1), w4p = 2 * w5p + (i & 1);
        f32x4 acc[2][4];
        #pragma unroll
        for (int a_ = 0; a_ < 2; a_++)
            #pragma unroll
            for (int b_ = 0; b_ < 4; b_++) acc[a_][b_] = zero;

        for (int tap = 0; tap < 4; tap++) {
            const int h3 = 2 * h4 + (tap >> 1), w3 = 2 * w4p + (tap & 1);
            WAIT_LGKM0();
            #pragma unroll
            for (int sl = 0; sl < 4; sl++) {
                const int ks = sl >> 1, mh = sl & 1;
                int b = mt * 32 + mh * 16 + lm;
                if (b >= Bc) b = Bc - 1;
                gl_lds16(xin + (sb + b) * 4096 + (h3 * 8 + w3) * 64 + ks * 32 + lq * 8,
                         &Aw[sl * 512]);
            }
            WAIT_VM0();
            #pragma unroll
            for (int ks = 0; ks < 2; ks++) {
                #pragma unroll
                for (int fm = 0; fm < 2; fm++) {
                    short8 a = *(const short8*)&Aw[(ks * 2 + fm) * 512 + lane * 8];
                    #pragma unroll
                    for (int fn = 0; fn < 4; fn++) {
                        short8 bfr = *(const short8*)&smem[(tap * 8 + ks * 4 + fn) * 512 + lane * 8];
                        acc[fm][fn] = __builtin_amdgcn_mfma_f32_16x16x32_bf16(a, bfr, acc[fm][fn], 0, 0, 0);
                    }
                }
            }
        }
        #pragma unroll
        for (int fm = 0; fm < 2; fm++) {
            #pragma unroll
            for (int fn = 0; fn < 4; fn++) {
                #pragma unroll
                for (int r = 0; r < 4; r++) {
                    const int m = fm * 16 + lq * 4 + r;
                    const int ch = fn * 16 + lm;
                    mid1w[m * 264 + i * 64 + ch] =
                        f2bf(fmaxf(acc[fm][fn][r] + sBias[ch], 0.f));
                }
            }
        }
    }

    // phase 2: L5 (wave-private)
    {
        f32x4 acc2[2][4];
        #pragma unroll
        for (int a_ = 0; a_ < 2; a_++)
            #pragma unroll
            for (int b_ = 0; b_ < 4; b_++) acc2[a_][b_] = zero;

        #pragma unroll
        for (int i = 0; i < 4; i++) {
            #pragma unroll
            for (int ks = 0; ks < 2; ks++) {
                short8 a0 = *(const short8*)&mid1w[lm * 264 + i * 64 + ks * 32 + lq * 8];
                short8 a1 = *(const short8*)&mid1w[(16 + lm) * 264 + i * 64 + ks * 32 + lq * 8];
                #pragma unroll
                for (int fn = 0; fn < 4; fn++) {
                    short8 bfr = *(const short8*)&smem[16384 + (i * 8 + ks * 4 + fn) * 512 + lane * 8];
                    acc2[0][fn] = __builtin_amdgcn_mfma_f32_16x16x32_bf16(a0, bfr, acc2[0][fn], 0, 0, 0);
                    acc2[1][fn] = __builtin_amdgcn_mfma_f32_16x16x32_bf16(a1, bfr, acc2[1][fn], 0, 0, 0);
                }
            }
        }
        #pragma unroll
        for (int fm = 0; fm < 2; fm++) {
            #pragma unroll
            for (int fn = 0; fn < 4; fn++) {
                #pragma unroll
                for (int r = 0; r < 4; r++) {
                    const int m = fm * 16 + lq * 4 + r;
                    const int ch = fn * 16 + lm;
                    mid1w[m * 72 + ch] =
                        f2bf(fmaxf(acc2[fm][fn][r] + sBias[64 + ch], 0.f));
                }
            }
        }
    }
    __syncthreads();

    {
        const ushort_t* w6s = w6 + (size_t)site * 16384;
        const ushort_t* wds = wd + (size_t)site * 8192;
        #pragma unroll
        for (int s2 = 0; s2 < 8; s2++) {
            const int s = wv * 8 + s2;
            gl_lds16(w6s + s * 512 + lane * 8, &smem[s * 512]);
        }
        #pragma unroll
        for (int s2 = 0; s2 < 4; s2++) {
            const int s = wv * 4 + s2;
            gl_lds16(wds + s * 512 + lane * 8, &smem[16384 + s * 512]);
        }
    }
    __syncthreads();

    // phase 3: L6
    {
        f32x4 acc3[2];
        acc3[0] = zero; acc3[1] = zero;
        #pragma unroll
        for (int tap = 0; tap < 4; tap++) {
            const ushort_t* sl = smem + 32768 + tap * 8448;
            #pragma unroll
            for (int ks = 0; ks < 2; ks++) {
                short8 a0 = *(const short8*)&sl[lm * 72 + ks * 32 + lq * 8];
                short8 a1 = *(const short8*)&sl[(16 + lm) * 72 + ks * 32 + lq * 8];
                short8 bfr = *(const short8*)&smem[(tap * 8 + ks * 4 + wv) * 512 + lane * 8];
                acc3[0] = __builtin_amdgcn_mfma_f32_16x16x32_bf16(a0, bfr, acc3[0], 0, 0, 0);
                acc3[1] = __builtin_amdgcn_mfma_f32_16x16x32_bf16(a1, bfr, acc3[1], 0, 0, 0);
            }
        }
        ushort_t* mid3 = smem + 66560;
        #pragma unroll
        for (int fm = 0; fm < 2; fm++) {
            #pragma unroll
            for (int r = 0; r < 4; r++) {
                const int m = fm * 16 + lq * 4 + r;
                const int ch = wv * 16 + lm;
                mid3[m * 72 + ch] =
                    f2bf(fmaxf(acc3[fm][r] + sBias[128 + ch], 0.f));
            }
        }
    }
    __syncthreads();

    // phase 4: final projection
    {
        const ushort_t* mid3 = smem + 66560;
        f32x4 acc4[2][2];
        acc4[0][0] = zero; acc4[0][1] = zero; acc4[1][0] = zero; acc4[1][1] = zero;
        #pragma unroll
        for (int ks = 0; ks < 2; ks++) {
            short8 a0 = *(const short8*)&mid3[lm * 72 + ks * 32 + lq * 8];
            short8 a1 = *(const short8*)&mid3[(16 + lm) * 72 + ks * 32 + lq * 8];
            #pragma unroll
            for (int n2 = 0; n2 < 2; n2++) {
                const int nh = 2 * wv + n2;
                short8 bfr = *(const short8*)&smem[16384 + (ks * 8 + nh) * 512 + lane * 8];
                acc4[0][n2] = __builtin_amdgcn_mfma_f32_16x16x32_bf16(a0, bfr, acc4[0][n2], 0, 0, 0);
                acc4[1][n2] = __builtin_amdgcn_mfma_f32_16x16x32_bf16(a1, bfr, acc4[1][n2], 0, 0, 0);
            }
        }
        #pragma unroll
        for (int fm = 0; fm < 2; fm++) {
            #pragma unroll
            for (int n2 = 0; n2 < 2; n2++) {
                const int n = (2 * wv + n2) * 16 + lm;
                const int rr = n >> 6, ou = (n >> 3) & 7, ov = n & 7;
                const size_t obase =
                    (((size_t)(u * 8 + ou)) * 64 + (v * 8 + ov)) * 2 + rr;
                #pragma unroll
                for (int reg = 0; reg < 4; reg++) {
                    const int brow = mt * 32 + fm * 16 + lq * 4 + reg;
                    if (brow < Bc) {
                        const size_t oidx = obase + (size_t)(b_off + brow) * 8192;
                        if (isbf) ((__hip_bfloat16*)out)[oidx] =
                            __float2bfloat16(acc4[fm][n2][reg]);
                        else ((float*)out)[oidx] = acc4[fm][n2][reg];
                    }
                }
            }
        }
    }
}

// ---------------------------------------------------------------------------
extern "C" void kernel_launch(void* const* d_in, const int* in_sizes, int n_in,
                              void* d_out, int out_size, void* d_ws, size_t ws_size,
                              hipStream_t stream)
{
    (void)in_sizes; (void)n_in; (void)out_size;

    const void* in_data = d_in[0];
    const void* filt    = d_in[1];
    const void* bias0   = d_in[2];
    const void* fl[7];
    const void* bl[7];
    for (int l = 1; l <= 6; l++) {
        fl[l] = d_in[1 + 2 * l];
        bl[l] = d_in[2 + 2 * l];
    }
    const void* Wd = d_in[15];

    const int Bfull = 128;
    const size_t perB = (size_t)64 * 64 * 64;

    const size_t wbufBytes  = 565248ull * 16;
    const size_t wdbufBytes = 65536ull * 16;
    const size_t bbufBytes  = 17664ull * 4;
    const size_t headBytes  = 256 + wbufBytes + wdbufBytes + bbufBytes;

    const size_t avail = ws_size > headBytes ? ws_size - headBytes : 0;
    int Bc = 0;
    for (int c = 128; c >= 1; c >>= 1) {
        if ((size_t)2 * c * perB * sizeof(__hip_bfloat16) <= avail) { Bc = c; break; }
    }
    if (Bc == 0) return;

    int* flag = (int*)d_ws;
    ushort_t* wbuf  = (ushort_t*)((char*)d_ws + 256);
    ushort_t* wdbuf = (ushort_t*)((char*)d_ws + 256 + wbufBytes);
    float* bbuf = (float*)((char*)d_ws + 256 + wbufBytes + wdbufBytes);
    __hip_bfloat16* bufA = (__hip_bfloat16*)((char*)d_ws + headBytes);
    __hip_bfloat16* bufB = bufA + (size_t)Bc * perB;

    static const size_t w_off[7] = {0, 0, 65536, 327680, 1376256, 2424832, 3473408};
    static const int    b_off_tab[7] = {0, 0, 256, 1280, 5376, 9472, 13568};

    k_prep<<<dim3(2533), 256, 0, stream>>>(
        (const uint32_t*)in_data,
        fl[1], fl[2], fl[3], fl[4], fl[5], fl[6], Wd,
        bl[1], bl[2], bl[3], bl[4], bl[5], bl[6],
        wbuf, wdbuf, bbuf, flag);

    const int mt4 = (Bc + 63) / 64;
    const int mt32 = (Bc + 31) / 32;

    for (int b_off = 0; b_off < Bfull; b_off += Bc) {
        // fused patch-embed + L1 -> bufA
        k_s01<<<dim3(1024 * mt32), 256, 0, stream>>>(
            in_data, filt, bias0, wbuf + w_off[1], bbuf + b_off_tab[1],
            bufA, flag, Bc, b_off, mt32);

        __hip_bfloat16* cur = bufA;
        __hip_bfloat16* nxt = bufB;
        for (int lvl = 2; lvl <= 3; lvl++) {
            const int Nu = 1 << lvl;
            const int H  = 64 >> lvl;
            const int Nv_in = Nu >> 1;
            dim3 grid(Nv_in * Nv_in * H * H * mt4);
            k_level4<<<grid, 256, 0, stream>>>(cur, wbuf + w_off[lvl],
                bbuf + b_off_tab[lvl], nxt, Nu, H, Bc, mt4);
            __hip_bfloat16* tmp = cur; cur = nxt; nxt = tmp;
        }

        k_f456<<<dim3(64 * mt32), 256, 0, stream>>>(cur,
            wbuf + w_off[4], wbuf + w_off[5], wbuf + w_off[6], wdbuf,
            bbuf + b_off_tab[4], bbuf + b_off_tab[5], bbuf + b_off_tab[6],
            d_out, flag, Bc, b_off, mt32);
    }
}

// Round 8
// 269.730 us; speedup vs baseline: 1.0067x; 1.0067x over previous
//
#include <hip/hip_runtime.h>
#include <hip/hip_bf16.h>
#include <cstdint>
#include <cstddef>

// ButterflyLayer2D on MI355X.
// k_s01 = fused patch-embed + level-1 (conflict-free padded patch LDS,
// B-fragments loaded global->VGPR directly) -> levels 2-3 as bf16 MFMA GEMMs
// (4-children A-sharing) -> k_f456 = fused L4+L5+L6+final.
// Weights pre-transposed once into MFMA B-fragment layout (bf16) in d_ws.

typedef __attribute__((ext_vector_type(8))) short short8;
typedef __attribute__((ext_vector_type(4))) float f32x4;
typedef unsigned short ushort_t;

static __device__ __forceinline__ float b2f(const __hip_bfloat16 x) {
    return __bfloat162float(x);
}
static __device__ __forceinline__ ushort_t f2bf(float x) {
    __hip_bfloat16 h = __float2bfloat16(x);
    ushort_t u;
    __builtin_memcpy(&u, &h, 2);
    return u;
}
static __device__ __forceinline__ void gl_lds16(const void* g, void* l) {
    __builtin_amdgcn_global_load_lds(
        (const __attribute__((address_space(1))) void*)g,
        (__attribute__((address_space(3))) void*)l, 16, 0, 0);
}
// gfx9 waitcnt encodings: lgkmcnt(0) only / vmcnt(0) only
#define WAIT_LGKM0() __builtin_amdgcn_s_waitcnt(0xC07F)
#define WAIT_VM0()   __builtin_amdgcn_s_waitcnt(0x0F70)

// ---------------------------------------------------------------------------
// k_prep: merged dtype-detect + weight transpose + bias convert (verified r6).
// gid ranges: [0,565248) level weights; [565248,630784) Wd; [630784,648448) bias.
// ---------------------------------------------------------------------------
__global__ __launch_bounds__(256) void k_prep(
    const uint32_t* __restrict__ in_words,
    const void* f1, const void* f2, const void* f3,
    const void* f4, const void* f5, const void* f6, const void* wdsrc,
    const void* b1, const void* b2, const void* b3,
    const void* b4, const void* b5, const void* b6,
    ushort_t* __restrict__ wbuf, ushort_t* __restrict__ wdbuf,
    float* __restrict__ bbuf, int* __restrict__ flag)
{
    __shared__ int sflag;
    const int t = threadIdx.x;
    if (t < 64) {
        const float v = __uint_as_float(in_words[t]);
        const bool plaus = (v == 0.0f) || (fabsf(v) > 1e-8f && fabsf(v) < 1e4f);
        const unsigned long long m = __ballot(plaus);
        if (t == 0) sflag = (__popcll(m) >= 48) ? 0 : 1;
    }
    __syncthreads();
    const int isbf = sflag;
    const int gid = blockIdx.x * 256 + t;
    if (blockIdx.x == 0 && t == 0) *flag = isbf;

    if (gid >= 648448) return;
    if (gid >= 630784) {
        const int bg = gid - 630784;
        const void* src; int base;
        if      (bg <   256) { src = b1; base = 0;     }
        else if (bg <  1280) { src = b2; base = 256;   }
        else if (bg <  5376) { src = b3; base = 1280;  }
        else if (bg <  9472) { src = b4; base = 5376;  }
        else if (bg < 13568) { src = b5; base = 9472;  }
        else                 { src = b6; base = 13568; }
        const int local = bg - base;
        bbuf[bg] = isbf ? b2f(((const __hip_bfloat16*)src)[local])
                        : ((const float*)src)[local];
        return;
    }
    if (gid >= 565248) {
        const int local = gid - 565248;
        const int lane = local & 63;
        const int slot = (local >> 6) & 15;
        const int site = local >> 10;
        const int ks2 = slot >> 3, nh = slot & 7, q = lane >> 4;
        const int n = nh * 16 + (lane & 15);
        const int r = n >> 6, kk = n & 63;
        const int cbase = ks2 * 32 + q * 8;
        ushort_t pk[8];
        if (isbf) {
            const ushort_t* s = (const ushort_t*)wdsrc;
            #pragma unroll
            for (int j = 0; j < 8; j++)
                pk[j] = s[(((size_t)(site * 2 + r) * 64 + cbase + j) * 64) + kk];
        } else {
            const float* s = (const float*)wdsrc;
            #pragma unroll
            for (int j = 0; j < 8; j++)
                pk[j] = f2bf(s[(((size_t)(site * 2 + r) * 64 + cbase + j) * 64) + kk]);
        }
        *(uint4*)&wdbuf[(size_t)local * 8] = *(uint4*)pk;
        return;
    }
    const void* fsrc; int base;
    if      (gid <   8192) { fsrc = f1; base = 0;      }
    else if (gid <  40960) { fsrc = f2; base = 8192;   }
    else if (gid < 172032) { fsrc = f3; base = 40960;  }
    else if (gid < 303104) { fsrc = f4; base = 172032; }
    else if (gid < 434176) { fsrc = f5; base = 303104; }
    else                   { fsrc = f6; base = 434176; }
    const int local = gid - base;
    const int lane = local & 63;
    const int slot = (local >> 6) & 7;
    const int sitetap = local >> 9;
    const int ks = slot >> 2, nh = slot & 3, q = lane >> 4;
    const int n = (lane & 15) + nh * 16;
    const int kbase = ks * 32 + q * 8;
    ushort_t pk[8];
    if (isbf) {
        const ushort_t* s = (const ushort_t*)fsrc + (size_t)sitetap * 4096;
        #pragma unroll
        for (int j = 0; j < 8; j++) pk[j] = s[(kbase + j) * 64 + n];
    } else {
        const float* s = (const float*)fsrc + (size_t)sitetap * 4096;
        #pragma unroll
        for (int j = 0; j < 8; j++) pk[j] = f2bf(s[(kbase + j) * 64 + n]);
    }
    *(uint4*)&wbuf[(size_t)gid * 8] = *(uint4*)pk;
}

// ---------------------------------------------------------------------------
// k_s01: fused patch-embed + level 1 (round-8 rework).
// Block = (L1 position (h,w) in 32x32, 32-batch mtile). Waves = 4 children.
//  1. stage 8x8 f32 patch per batch row into padded sIn (stride 68: the 8
//     vb-rows per ds_read land on disjoint bank quads -> conflict-free)
//  2. VALU patch-embed -> bf16 A-frags in LDS (fragment-major)
//  3. MFMA: B-frags loaded DIRECTLY global->VGPR (wbuf layout is contiguous
//     per (slot,lane); 64 KB, L2-hot) -- no LDS staging, no waitcnt macros
//  4. barrier (A dead), per-wave epilogue via aliased LDS region
// ---------------------------------------------------------------------------
__global__ __launch_bounds__(256, 2) void k_s01(
    const void* __restrict__ in_data,   // (128,256,256,1)
    const void* __restrict__ filt,      // (4,4,1,64)
    const void* __restrict__ bias0,     // (64)
    const ushort_t* __restrict__ w1,    // wbuf + L1 offset (site=child, 4*4096)
    const float* __restrict__ b1,       // bbuf + L1 offset
    __hip_bfloat16* __restrict__ xout,  // (4, Bc, 32,32,64)
    const int* __restrict__ flag, int Bc, int b_off, int mtiles)
{
    const int isbf = *flag;
    int idx = blockIdx.x;
    const int mt = idx % mtiles; idx /= mtiles;
    const int w = idx & 31;
    const int h = idx >> 5;

    // LDS pool (ushort units):
    //   A   [0, 8192)      : 4 taps x 4 slots x 512  (16 KB)
    //   IN  [8192, 12544)  : f32[32][stride 68] patch (8704 B)
    //   F   [12544, 14592) : f32[16][64] filter (4 KB)
    //   epi [wv*2176, +2176) aliases A+IN after the post-MFMA barrier
    __shared__ ushort_t smem[14592];
    __shared__ float sB0[64];
    __shared__ float sBias[4][64];

    float* sIn = (float*)&smem[8192];     // row stride 68 floats
    float* sF  = (float*)&smem[12544];    // row stride 64 floats

    const int t = threadIdx.x;
    const int wave = t >> 6, lane = t & 63;
    const int lm = lane & 15, lq = lane >> 4;

    // small tables
    if (isbf) {
        const __hip_bfloat16* fsrc = (const __hip_bfloat16*)filt;
        #pragma unroll
        for (int i = 0; i < 4; i++) {
            int flat = i * 256 + t;
            sF[(flat >> 6) * 64 + (flat & 63)] = b2f(fsrc[flat]);
        }
        if (t < 64) sB0[t] = b2f(((const __hip_bfloat16*)bias0)[t]);
    } else {
        const float* fsrc = (const float*)filt;
        #pragma unroll
        for (int i = 0; i < 4; i++) {
            int flat = i * 256 + t;
            sF[(flat >> 6) * 64 + (flat & 63)] = fsrc[flat];
        }
        if (t < 64) sB0[t] = ((const float*)bias0)[t];
    }
    sBias[t >> 6][t & 63] = b1[(t >> 6) * 64 + (t & 63)];

    // 1. stage input patch (padded rows -> conflict-free writes)
    #pragma unroll
    for (int i = 0; i < 2; i++) {
        const int task = i * 256 + t;        // 512 float4 tasks
        const int half = task & 1, r = (task >> 1) & 7, b = task >> 4;
        int bl = mt * 32 + b;
        if (bl >= Bc) bl = Bc - 1;
        const size_t off = ((size_t)(b_off + bl) * 256 + 8 * h + r) * 256
                         + 8 * w + half * 4;
        float4 val;
        if (isbf) {
            const __hip_bfloat16* s = (const __hip_bfloat16*)in_data + off;
            val.x = b2f(s[0]); val.y = b2f(s[1]); val.z = b2f(s[2]); val.w = b2f(s[3]);
        } else {
            val = *(const float4*)((const float*)in_data + off);
        }
        *(float4*)&sIn[b * 68 + r * 8 + half * 4] = val;
    }
    __syncthreads();

    // 2. VALU patch-embed: thread = (vb, oct); 4 taps x 8 ch x 16 MAC
    {
        const int vb = t >> 3, oct = t & 7;
        float4 pf[16][2];
        #pragma unroll
        for (int pq = 0; pq < 16; pq++) {
            pf[pq][0] = *(const float4*)&sF[pq * 64 + oct * 8];
            pf[pq][1] = *(const float4*)&sF[pq * 64 + oct * 8 + 4];
        }
        const int ks = oct >> 2;
        const int slot = ks * 2 + (vb >> 4);
        const int ln = (vb & 15) | ((oct & 3) << 4);
        #pragma unroll
        for (int tap = 0; tap < 4; tap++) {
            const int x = tap >> 1, y = tap & 1;
            float4 rin[4];
            #pragma unroll
            for (int p = 0; p < 4; p++)
                rin[p] = *(const float4*)&sIn[vb * 68 + (4 * x + p) * 8 + 4 * y];
            float acc8[8];
            #pragma unroll
            for (int j = 0; j < 8; j++) acc8[j] = sB0[oct * 8 + j];
            #pragma unroll
            for (int p = 0; p < 4; p++) {
                #pragma unroll
                for (int q = 0; q < 4; q++) {
                    const float a = ((const float*)&rin[p])[q];
                    const float* fp = (const float*)&pf[p * 4 + q][0];
                    #pragma unroll
                    for (int j = 0; j < 8; j++)
                        acc8[j] = fmaf(a, fp[j], acc8[j]);
                }
            }
            ushort_t pk[8];
            #pragma unroll
            for (int j = 0; j < 8; j++) pk[j] = f2bf(fmaxf(acc8[j], 0.f));
            *(uint4*)&smem[((tap * 4 + slot) * 64 + ln) * 8] = *(uint4*)pk;
        }
    }
    __syncthreads();

    // 3. MFMA: B-frags direct global->VGPR (no LDS staging)
    const f32x4 zero = {0.f, 0.f, 0.f, 0.f};
    f32x4 accm[2][4];
    #pragma unroll
    for (int i = 0; i < 2; i++)
        #pragma unroll
        for (int j = 0; j < 4; j++) accm[i][j] = zero;

    const ushort_t* wsite = w1 + (size_t)wave * 16384;   // so == wave
    for (int tap = 0; tap < 4; tap++) {
        short8 bfr[2][4];
        #pragma unroll
        for (int ks = 0; ks < 2; ks++)
            #pragma unroll
            for (int fn = 0; fn < 4; fn++)
                bfr[ks][fn] = *(const short8*)(wsite + (size_t)tap * 4096
                                               + (ks * 4 + fn) * 512 + lane * 8);
        #pragma unroll
        for (int ks = 0; ks < 2; ks++) {
            #pragma unroll
            for (int fm = 0; fm < 2; fm++) {
                short8 a = *(const short8*)&smem[((tap * 4 + ks * 2 + fm) * 64 + lane) * 8];
                #pragma unroll
                for (int fn = 0; fn < 4; fn++)
                    accm[fm][fn] = __builtin_amdgcn_mfma_f32_16x16x32_bf16(
                        a, bfr[ks][fn], accm[fm][fn], 0, 0, 0);
            }
        }
    }
    __syncthreads();   // all waves done reading A -> epi may alias

    // 4. epilogue: bias1 + relu -> bf16 via wave-private aliased LDS
    {
        float bv[4];
        #pragma unroll
        for (int fn = 0; fn < 4; fn++) bv[fn] = sBias[wave][fn * 16 + lm];
        ushort_t* epi = &smem[wave * 2176];   // 32 rows x stride 68
        #pragma unroll
        for (int fm = 0; fm < 2; fm++) {
            #pragma unroll
            for (int fn = 0; fn < 4; fn++) {
                #pragma unroll
                for (int r = 0; r < 4; r++) {
                    const int row = fm * 16 + lq * 4 + r;
                    epi[row * 68 + fn * 16 + lm] =
                        f2bf(fmaxf(accm[fm][fn][r] + bv[fn], 0.f));
                }
            }
        }
        const size_t ostride = (size_t)32 * 32 * 64;
        const size_t obase = (size_t)wave * Bc * ostride + ((size_t)h * 32 + w) * 64;
        #pragma unroll
        for (int i = 0; i < 4; i++) {
            const int task = i * 64 + lane;
            const int oc = task & 7, row = task >> 3;
            const int b = mt * 32 + row;
            if (b < Bc) {
                *(uint4*)(xout + obase + (size_t)b * ostride + oc * 8) =
                    *(const uint4*)&epi[row * 68 + oc * 8];
            }
        }
    }
}

// ---------------------------------------------------------------------------
// Repeat level (2-3), verified rounds 4-7: block = (parent site, h, w, mtile
// of 64), wave = child; A fetched once for the 4 children.
// ---------------------------------------------------------------------------
__global__ __launch_bounds__(256) void k_level4(
    const __hip_bfloat16* __restrict__ xin,
    const ushort_t* __restrict__ wbuf,
    const float* __restrict__ bbuf,
    __hip_bfloat16* __restrict__ xout,
    int Nv_out, int HW, int Bc, int mtiles)
{
    __shared__ ushort_t smem[20480];
    __shared__ float sBias[4][64];
    ushort_t* sA = smem;
    ushort_t* sB = smem + 4096;

    int idx = blockIdx.x;
    const int mt = idx % mtiles; idx /= mtiles;
    const int w  = idx % HW; idx /= HW;
    const int h  = idx % HW; idx /= HW;
    const int Nv_in = Nv_out >> 1;
    const int vp = idx % Nv_in;
    const int up = idx / Nv_in;

    const int t = threadIdx.x;
    const int wave = t >> 6, lane = t & 63;
    const int lm = lane & 15, lq = lane >> 4;

    {
        const int ct = t >> 6, o = t & 63;
        const int so_t = (2 * up + (ct >> 1)) * Nv_out + (2 * vp + (ct & 1));
        sBias[ct][o] = bbuf[so_t * 64 + o];
    }

    const int so = (2 * up + (wave >> 1)) * Nv_out + (2 * vp + (wave & 1));
    const int H_in = HW * 2;
    const size_t bstride = (size_t)H_in * H_in * 64;
    const size_t siteb = (size_t)(up * Nv_in + vp) * Bc * bstride;
    const ushort_t* wsite = wbuf + (size_t)so * 4 * 4096;

    const f32x4 zero = {0.f, 0.f, 0.f, 0.f};
    f32x4 acc[4][4];
    #pragma unroll
    for (int i = 0; i < 4; i++)
        #pragma unroll
        for (int j = 0; j < 4; j++) acc[i][j] = zero;

    for (int tap = 0; tap < 4; tap++) {
        const int hi = 2 * h + (tap >> 1), wi = 2 * w + (tap & 1);
        const size_t tapoff = siteb + ((size_t)hi * H_in + wi) * 64;
        #pragma unroll
        for (int s2 = 0; s2 < 2; s2++) {
            const int s = wave * 2 + s2;
            const int ks = s >> 2, mh = s & 3;
            int b = mt * 64 + lm + mh * 16;
            if (b >= Bc) b = Bc - 1;
            gl_lds16(xin + tapoff + (size_t)b * bstride + ks * 32 + lq * 8,
                     &sA[s * 512]);
        }
        const ushort_t* wt = wsite + (size_t)tap * 4096;
        #pragma unroll
        for (int s = 0; s < 8; s++) {
            gl_lds16(wt + s * 512 + lane * 8, &sB[wave * 4096 + s * 512]);
        }
        __syncthreads();

        #pragma unroll
        for (int ks = 0; ks < 2; ks++) {
            short8 bf0 = *(const short8*)&sB[wave * 4096 + (ks * 4 + 0) * 512 + lane * 8];
            short8 bf1 = *(const short8*)&sB[wave * 4096 + (ks * 4 + 1) * 512 + lane * 8];
            short8 bf2 = *(const short8*)&sB[wave * 4096 + (ks * 4 + 2) * 512 + lane * 8];
            short8 bf3 = *(const short8*)&sB[wave * 4096 + (ks * 4 + 3) * 512 + lane * 8];
            #pragma unroll
            for (int fm = 0; fm < 4; fm++) {
                short8 a = *(const short8*)&sA[(ks * 4 + fm) * 512 + lane * 8];
                acc[fm][0] = __builtin_amdgcn_mfma_f32_16x16x32_bf16(a, bf0, acc[fm][0], 0, 0, 0);
                acc[fm][1] = __builtin_amdgcn_mfma_f32_16x16x32_bf16(a, bf1, acc[fm][1], 0, 0, 0);
                acc[fm][2] = __builtin_amdgcn_mfma_f32_16x16x32_bf16(a, bf2, acc[fm][2], 0, 0, 0);
                acc[fm][3] = __builtin_amdgcn_mfma_f32_16x16x32_bf16(a, bf3, acc[fm][3], 0, 0, 0);
            }
        }
        __syncthreads();
    }

    float bv[4];
    #pragma unroll
    for (int fn = 0; fn < 4; fn++) bv[fn] = sBias[wave][fn * 16 + lm];
    ushort_t* so_buf = smem + wave * 4352;
    #pragma unroll
    for (int fm = 0; fm < 4; fm++) {
        #pragma unroll
        for (int fn = 0; fn < 4; fn++) {
            #pragma unroll
            for (int r = 0; r < 4; r++) {
                const int row = fm * 16 + lq * 4 + r;
                so_buf[row * 68 + fn * 16 + lm] =
                    f2bf(fmaxf(acc[fm][fn][r] + bv[fn], 0.f));
            }
        }
    }
    __syncthreads();

    const size_t ostride = (size_t)HW * HW * 64;
    const size_t obase = (size_t)so * Bc * ostride + ((size_t)h * HW + w) * 64;
    #pragma unroll
    for (int i = 0; i < 8; i++) {
        const int task = i * 64 + lane;
        const int oct = task & 7, row = task >> 3;
        const int b = mt * 64 + row;
        if (b < Bc) {
            *(uint4*)(xout + obase + (size_t)b * ostride + oct * 8) =
                *(const uint4*)&so_buf[row * 68 + oct * 8];
        }
    }
}

// ---------------------------------------------------------------------------
// k_f456: fused L4 + L5 + L6 + final (verified round 6).
// ---------------------------------------------------------------------------
__global__ __launch_bounds__(256, 1) void k_f456(
    const __hip_bfloat16* __restrict__ xin,   // L3 out: (64, Bc, 8,8,64)
    const ushort_t* __restrict__ w4, const ushort_t* __restrict__ w5,
    const ushort_t* __restrict__ w6, const ushort_t* __restrict__ wd,
    const float* __restrict__ b4, const float* __restrict__ b5,
    const float* __restrict__ b6,
    void* __restrict__ out, const int* __restrict__ flag,
    int Bc, int b_off, int mtiles)
{
    const int isbf = *flag;
    const int bx = blockIdx.x;
    const int mt = bx % mtiles;
    const int site = bx / mtiles;
    const int u = site >> 3, v = site & 7;

    __shared__ ushort_t smem[74752];
    __shared__ float sBias[192];

    const int t = threadIdx.x;
    const int wv = t >> 6, lane = t & 63;
    const int lm = lane & 15, lq = lane >> 4;

    if (t < 64) {
        sBias[t]       = b4[site * 64 + t];
        sBias[64 + t]  = b5[site * 64 + t];
        sBias[128 + t] = b6[site * 64 + t];
    }

    {
        const ushort_t* w4s = w4 + (size_t)site * 16384;
        const ushort_t* w5s = w5 + (size_t)site * 16384;
        #pragma unroll
        for (int s2 = 0; s2 < 8; s2++) {
            const int s = wv * 8 + s2;
            gl_lds16(w4s + s * 512 + lane * 8, &smem[s * 512]);
            gl_lds16(w5s + s * 512 + lane * 8, &smem[16384 + s * 512]);
        }
    }
    __syncthreads();

    const f32x4 zero = {0.f, 0.f, 0.f, 0.f};
    const int h5 = wv >> 1, w5p = wv & 1;
    ushort_t* mid1w = smem + 32768 + wv * 8448;
    ushort_t* Aw = smem + 66560 + wv * 2048;
    const size_t sb = (size_t)site * Bc;

    // phase 1: L4
    for (int i = 0; i < 4; i++) {
        const int h4 = 2 * h5 + (i >> 1), w4p = 2 * w5p + (i & 1);
        f32x4 acc[2][4];
        #pragma unroll
        for (int a_ = 0; a_ < 2; a_++)
            #pragma unroll
            for (int b_ = 0; b_ < 4; b_++) acc[a_][b_] = zero;

        for (int tap = 0; tap < 4; tap++) {
            const int h3 = 2 * h4 + (tap >> 1), w3 = 2 * w4p + (tap & 1);
            WAIT_LGKM0();
            #pragma unroll
            for (int sl = 0; sl < 4; sl++) {
                const int ks = sl >> 1, mh = sl & 1;
                int b = mt * 32 + mh * 16 + lm;
                if (b >= Bc) b = Bc - 1;
                gl_lds16(xin + (sb + b) * 4096 + (h3 * 8 + w3) * 64 + ks * 32 + lq * 8,
                         &Aw[sl * 512]);
            }
            WAIT_VM0();
            #pragma unroll
            for (int ks = 0; ks < 2; ks++) {
                #pragma unroll
                for (int fm = 0; fm < 2; fm++) {
                    short8 a = *(const short8*)&Aw[(ks * 2 + fm) * 512 + lane * 8];
                    #pragma unroll
                    for (int fn = 0; fn < 4; fn++) {
                        short8 bfr = *(const short8*)&smem[(tap * 8 + ks * 4 + fn) * 512 + lane * 8];
                        acc[fm][fn] = __builtin_amdgcn_mfma_f32_16x16x32_bf16(a, bfr, acc[fm][fn], 0, 0, 0);
                    }
                }
            }
        }
        #pragma unroll
        for (int fm = 0; fm < 2; fm++) {
            #pragma unroll
            for (int fn = 0; fn < 4; fn++) {
                #pragma unroll
                for (int r = 0; r < 4; r++) {
                    const int m = fm * 16 + lq * 4 + r;
                    const int ch = fn * 16 + lm;
                    mid1w[m * 264 + i * 64 + ch] =
                        f2bf(fmaxf(acc[fm][fn][r] + sBias[ch], 0.f));
                }
            }
        }
    }

    // phase 2: L5 (wave-private)
    {
        f32x4 acc2[2][4];
        #pragma unroll
        for (int a_ = 0; a_ < 2; a_++)
            #pragma unroll
            for (int b_ = 0; b_ < 4; b_++) acc2[a_][b_] = zero;

        #pragma unroll
        for (int i = 0; i < 4; i++) {
            #pragma unroll
            for (int ks = 0; ks < 2; ks++) {
                short8 a0 = *(const short8*)&mid1w[lm * 264 + i * 64 + ks * 32 + lq * 8];
                short8 a1 = *(const short8*)&mid1w[(16 + lm) * 264 + i * 64 + ks * 32 + lq * 8];
                #pragma unroll
                for (int fn = 0; fn < 4; fn++) {
                    short8 bfr = *(const short8*)&smem[16384 + (i * 8 + ks * 4 + fn) * 512 + lane * 8];
                    acc2[0][fn] = __builtin_amdgcn_mfma_f32_16x16x32_bf16(a0, bfr, acc2[0][fn], 0, 0, 0);
                    acc2[1][fn] = __builtin_amdgcn_mfma_f32_16x16x32_bf16(a1, bfr, acc2[1][fn], 0, 0, 0);
                }
            }
        }
        #pragma unroll
        for (int fm = 0; fm < 2; fm++) {
            #pragma unroll
            for (int fn = 0; fn < 4; fn++) {
                #pragma unroll
                for (int r = 0; r < 4; r++) {
                    const int m = fm * 16 + lq * 4 + r;
                    const int ch = fn * 16 + lm;
                    mid1w[m * 72 + ch] =
                        f2bf(fmaxf(acc2[fm][fn][r] + sBias[64 + ch], 0.f));
                }
            }
        }
    }
    __syncthreads();

    {
        const ushort_t* w6s = w6 + (size_t)site * 16384;
        const ushort_t* wds = wd + (size_t)site * 8192;
        #pragma unroll
        for (int s2 = 0; s2 < 8; s2++) {
            const int s = wv * 8 + s2;
            gl_lds16(w6s + s * 512 + lane * 8, &smem[s * 512]);
        }
        #pragma unroll
        for (int s2 = 0; s2 < 4; s2++) {
            const int s = wv * 4 + s2;
            gl_lds16(wds + s * 512 + lane * 8, &smem[16384 + s * 512]);
        }
    }
    __syncthreads();

    // phase 3: L6
    {
        f32x4 acc3[2];
        acc3[0] = zero; acc3[1] = zero;
        #pragma unroll
        for (int tap = 0; tap < 4; tap++) {
            const ushort_t* sl = smem + 32768 + tap * 8448;
            #pragma unroll
            for (int ks = 0; ks < 2; ks++) {
                short8 a0 = *(const short8*)&sl[lm * 72 + ks * 32 + lq * 8];
                short8 a1 = *(const short8*)&sl[(16 + lm) * 72 + ks * 32 + lq * 8];
                short8 bfr = *(const short8*)&smem[(tap * 8 + ks * 4 + wv) * 512 + lane * 8];
                acc3[0] = __builtin_amdgcn_mfma_f32_16x16x32_bf16(a0, bfr, acc3[0], 0, 0, 0);
                acc3[1] = __builtin_amdgcn_mfma_f32_16x16x32_bf16(a1, bfr, acc3[1], 0, 0, 0);
            }
        }
        ushort_t* mid3 = smem + 66560;
        #pragma unroll
        for (int fm = 0; fm < 2; fm++) {
            #pragma unroll
            for (int r = 0; r < 4; r++) {
                const int m = fm * 16 + lq * 4 + r;
                const int ch = wv * 16 + lm;
                mid3[m * 72 + ch] =
                    f2bf(fmaxf(acc3[fm][r] + sBias[128 + ch], 0.f));
            }
        }
    }
    __syncthreads();

    // phase 4: final projection
    {
        const ushort_t* mid3 = smem + 66560;
        f32x4 acc4[2][2];
        acc4[0][0] = zero; acc4[0][1] = zero; acc4[1][0] = zero; acc4[1][1] = zero;
        #pragma unroll
        for (int ks = 0; ks < 2; ks++) {
            short8 a0 = *(const short8*)&mid3[lm * 72 + ks * 32 + lq * 8];
            short8 a1 = *(const short8*)&mid3[(16 + lm) * 72 + ks * 32 + lq * 8];
            #pragma unroll
            for (int n2 = 0; n2 < 2; n2++) {
                const int nh = 2 * wv + n2;
                short8 bfr = *(const short8*)&smem[16384 + (ks * 8 + nh) * 512 + lane * 8];
                acc4[0][n2] = __builtin_amdgcn_mfma_f32_16x16x32_bf16(a0, bfr, acc4[0][n2], 0, 0, 0);
                acc4[1][n2] = __builtin_amdgcn_mfma_f32_16x16x32_bf16(a1, bfr, acc4[1][n2], 0, 0, 0);
            }
        }
        #pragma unroll
        for (int fm = 0; fm < 2; fm++) {
            #pragma unroll
            for (int n2 = 0; n2 < 2; n2++) {
                const int n = (2 * wv + n2) * 16 + lm;
                const int rr = n >> 6, ou = (n >> 3) & 7, ov = n & 7;
                const size_t obase =
                    (((size_t)(u * 8 + ou)) * 64 + (v * 8 + ov)) * 2 + rr;
                #pragma unroll
                for (int reg = 0; reg < 4; reg++) {
                    const int brow = mt * 32 + fm * 16 + lq * 4 + reg;
                    if (brow < Bc) {
                        const size_t oidx = obase + (size_t)(b_off + brow) * 8192;
                        if (isbf) ((__hip_bfloat16*)out)[oidx] =
                            __float2bfloat16(acc4[fm][n2][reg]);
                        else ((float*)out)[oidx] = acc4[fm][n2][reg];
                    }
                }
            }
        }
    }
}

// ---------------------------------------------------------------------------
extern "C" void kernel_launch(void* const* d_in, const int* in_sizes, int n_in,
                              void* d_out, int out_size, void* d_ws, size_t ws_size,
                              hipStream_t stream)
{
    (void)in_sizes; (void)n_in; (void)out_size;

    const void* in_data = d_in[0];
    const void* filt    = d_in[1];
    const void* bias0   = d_in[2];
    const void* fl[7];
    const void* bl[7];
    for (int l = 1; l <= 6; l++) {
        fl[l] = d_in[1 + 2 * l];
        bl[l] = d_in[2 + 2 * l];
    }
    const void* Wd = d_in[15];

    const int Bfull = 128;
    const size_t perB = (size_t)64 * 64 * 64;

    const size_t wbufBytes  = 565248ull * 16;
    const size_t wdbufBytes = 65536ull * 16;
    const size_t bbufBytes  = 17664ull * 4;
    const size_t headBytes  = 256 + wbufBytes + wdbufBytes + bbufBytes;

    const size_t avail = ws_size > headBytes ? ws_size - headBytes : 0;
    int Bc = 0;
    for (int c = 128; c >= 1; c >>= 1) {
        if ((size_t)2 * c * perB * sizeof(__hip_bfloat16) <= avail) { Bc = c; break; }
    }
    if (Bc == 0) return;

    int* flag = (int*)d_ws;
    ushort_t* wbuf  = (ushort_t*)((char*)d_ws + 256);
    ushort_t* wdbuf = (ushort_t*)((char*)d_ws + 256 + wbufBytes);
    float* bbuf = (float*)((char*)d_ws + 256 + wbufBytes + wdbufBytes);
    __hip_bfloat16* bufA = (__hip_bfloat16*)((char*)d_ws + headBytes);
    __hip_bfloat16* bufB = bufA + (size_t)Bc * perB;

    static const size_t w_off[7] = {0, 0, 65536, 327680, 1376256, 2424832, 3473408};
    static const int    b_off_tab[7] = {0, 0, 256, 1280, 5376, 9472, 13568};

    k_prep<<<dim3(2533), 256, 0, stream>>>(
        (const uint32_t*)in_data,
        fl[1], fl[2], fl[3], fl[4], fl[5], fl[6], Wd,
        bl[1], bl[2], bl[3], bl[4], bl[5], bl[6],
        wbuf, wdbuf, bbuf, flag);

    const int mt4 = (Bc + 63) / 64;
    const int mt32 = (Bc + 31) / 32;

    for (int b_off = 0; b_off < Bfull; b_off += Bc) {
        // fused patch-embed + L1 -> bufA
        k_s01<<<dim3(1024 * mt32), 256, 0, stream>>>(
            in_data, filt, bias0, wbuf + w_off[1], bbuf + b_off_tab[1],
            bufA, flag, Bc, b_off, mt32);

        __hip_bfloat16* cur = bufA;
        __hip_bfloat16* nxt = bufB;
        for (int lvl = 2; lvl <= 3; lvl++) {
            const int Nu = 1 << lvl;
            const int H  = 64 >> lvl;
            const int Nv_in = Nu >> 1;
            dim3 grid(Nv_in * Nv_in * H * H * mt4);
            k_level4<<<grid, 256, 0, stream>>>(cur, wbuf + w_off[lvl],
                bbuf + b_off_tab[lvl], nxt, Nu, H, Bc, mt4);
            __hip_bfloat16* tmp = cur; cur = nxt; nxt = tmp;
        }

        k_f456<<<dim3(64 * mt32), 256, 0, stream>>>(cur,
            wbuf + w_off[4], wbuf + w_off[5], wbuf + w_off[6], wdbuf,
            bbuf + b_off_tab[4], bbuf + b_off_tab[5], bbuf + b_off_tab[6],
            d_out, flag, Bc, b_off, mt32);
    }
}

// Round 9
// 259.347 us; speedup vs baseline: 1.0470x; 1.0400x over previous
//
#include <hip/hip_runtime.h>
#include <hip/hip_bf16.h>
#include <cstdint>
#include <cstddef>

// ButterflyLayer2D on MI355X.
// k_stage0 (VALU patch-embed) -> k_level4 (L1, 4-children A-sharing) ->
// k_L23 = fused L2+L3 (phase1: wave=L2 position, wave-private A staging;
// phase2: wave=L3 child site, taps from LDS) -> k_f456 = fused L4+L5+L6+final.
// Weights pre-transposed once into MFMA B-fragment layout (bf16) in d_ws.

typedef __attribute__((ext_vector_type(8))) short short8;
typedef __attribute__((ext_vector_type(4))) float f32x4;
typedef unsigned short ushort_t;

static __device__ __forceinline__ float b2f(const __hip_bfloat16 x) {
    return __bfloat162float(x);
}
static __device__ __forceinline__ ushort_t f2bf(float x) {
    __hip_bfloat16 h = __float2bfloat16(x);
    ushort_t u;
    __builtin_memcpy(&u, &h, 2);
    return u;
}
static __device__ __forceinline__ void gl_lds16(const void* g, void* l) {
    __builtin_amdgcn_global_load_lds(
        (const __attribute__((address_space(1))) void*)g,
        (__attribute__((address_space(3))) void*)l, 16, 0, 0);
}
// gfx9 waitcnt encodings: lgkmcnt(0) only / vmcnt(0) only
#define WAIT_LGKM0() __builtin_amdgcn_s_waitcnt(0xC07F)
#define WAIT_VM0()   __builtin_amdgcn_s_waitcnt(0x0F70)

// ---------------------------------------------------------------------------
// k_prep: merged dtype-detect + weight transpose + bias convert (verified r6).
// gid ranges: [0,565248) level weights; [565248,630784) Wd; [630784,648448) bias.
// ---------------------------------------------------------------------------
__global__ __launch_bounds__(256) void k_prep(
    const uint32_t* __restrict__ in_words,
    const void* f1, const void* f2, const void* f3,
    const void* f4, const void* f5, const void* f6, const void* wdsrc,
    const void* b1, const void* b2, const void* b3,
    const void* b4, const void* b5, const void* b6,
    ushort_t* __restrict__ wbuf, ushort_t* __restrict__ wdbuf,
    float* __restrict__ bbuf, int* __restrict__ flag)
{
    __shared__ int sflag;
    const int t = threadIdx.x;
    if (t < 64) {
        const float v = __uint_as_float(in_words[t]);
        const bool plaus = (v == 0.0f) || (fabsf(v) > 1e-8f && fabsf(v) < 1e4f);
        const unsigned long long m = __ballot(plaus);
        if (t == 0) sflag = (__popcll(m) >= 48) ? 0 : 1;
    }
    __syncthreads();
    const int isbf = sflag;
    const int gid = blockIdx.x * 256 + t;
    if (blockIdx.x == 0 && t == 0) *flag = isbf;

    if (gid >= 648448) return;
    if (gid >= 630784) {
        const int bg = gid - 630784;
        const void* src; int base;
        if      (bg <   256) { src = b1; base = 0;     }
        else if (bg <  1280) { src = b2; base = 256;   }
        else if (bg <  5376) { src = b3; base = 1280;  }
        else if (bg <  9472) { src = b4; base = 5376;  }
        else if (bg < 13568) { src = b5; base = 9472;  }
        else                 { src = b6; base = 13568; }
        const int local = bg - base;
        bbuf[bg] = isbf ? b2f(((const __hip_bfloat16*)src)[local])
                        : ((const float*)src)[local];
        return;
    }
    if (gid >= 565248) {
        const int local = gid - 565248;
        const int lane = local & 63;
        const int slot = (local >> 6) & 15;
        const int site = local >> 10;
        const int ks2 = slot >> 3, nh = slot & 7, q = lane >> 4;
        const int n = nh * 16 + (lane & 15);
        const int r = n >> 6, kk = n & 63;
        const int cbase = ks2 * 32 + q * 8;
        ushort_t pk[8];
        if (isbf) {
            const ushort_t* s = (const ushort_t*)wdsrc;
            #pragma unroll
            for (int j = 0; j < 8; j++)
                pk[j] = s[(((size_t)(site * 2 + r) * 64 + cbase + j) * 64) + kk];
        } else {
            const float* s = (const float*)wdsrc;
            #pragma unroll
            for (int j = 0; j < 8; j++)
                pk[j] = f2bf(s[(((size_t)(site * 2 + r) * 64 + cbase + j) * 64) + kk]);
        }
        *(uint4*)&wdbuf[(size_t)local * 8] = *(uint4*)pk;
        return;
    }
    const void* fsrc; int base;
    if      (gid <   8192) { fsrc = f1; base = 0;      }
    else if (gid <  40960) { fsrc = f2; base = 8192;   }
    else if (gid < 172032) { fsrc = f3; base = 40960;  }
    else if (gid < 303104) { fsrc = f4; base = 172032; }
    else if (gid < 434176) { fsrc = f5; base = 303104; }
    else                   { fsrc = f6; base = 434176; }
    const int local = gid - base;
    const int lane = local & 63;
    const int slot = (local >> 6) & 7;
    const int sitetap = local >> 9;
    const int ks = slot >> 2, nh = slot & 3, q = lane >> 4;
    const int n = (lane & 15) + nh * 16;
    const int kbase = ks * 32 + q * 8;
    ushort_t pk[8];
    if (isbf) {
        const ushort_t* s = (const ushort_t*)fsrc + (size_t)sitetap * 4096;
        #pragma unroll
        for (int j = 0; j < 8; j++) pk[j] = s[(kbase + j) * 64 + n];
    } else {
        const float* s = (const float*)fsrc + (size_t)sitetap * 4096;
        #pragma unroll
        for (int j = 0; j < 8; j++) pk[j] = f2bf(s[(kbase + j) * 64 + n]);
    }
    *(uint4*)&wbuf[(size_t)gid * 8] = *(uint4*)pk;
}

// ---------------------------------------------------------------------------
// Stage 0 (verified rounds 5-6): patch-embed, register-tiled, bf16 out.
// ---------------------------------------------------------------------------
__global__ __launch_bounds__(256) void k_stage0(
    const void* __restrict__ in_data, const void* __restrict__ filt,
    const void* __restrict__ bias, __hip_bfloat16* __restrict__ x0,
    const int* __restrict__ flag, int b_off)
{
    const int isbf = *flag;
    const int blk = blockIdx.x;
    const int X  = blk & 63;
    const int bl = blk >> 6;
    const int bg = bl + b_off;

    __shared__ float sIn[4][256];
    __shared__ float sF[16][64];
    __shared__ float sB[64];

    const int t = threadIdx.x;
    const size_t srow = ((size_t)bg * 256 + (size_t)X * 4) * 256;

    if (isbf) {
        const __hip_bfloat16* src = (const __hip_bfloat16*)in_data + srow;
        #pragma unroll
        for (int i = 0; i < 4; i++) {
            int flat = i * 256 + t;
            int p = flat >> 8, col = flat & 255;
            sIn[p][col] = b2f(src[(size_t)p * 256 + col]);
        }
        const __hip_bfloat16* fsrc = (const __hip_bfloat16*)filt;
        #pragma unroll
        for (int i = 0; i < 4; i++) {
            int flat = i * 256 + t;
            sF[flat >> 6][flat & 63] = b2f(fsrc[flat]);
        }
        if (t < 64) sB[t] = b2f(((const __hip_bfloat16*)bias)[t]);
    } else {
        const float* src = (const float*)in_data + srow;
        const int p = t >> 6, c4 = (t & 63) * 4;
        *(float4*)&sIn[p][c4] = *(const float4*)(src + (size_t)p * 256 + c4);
        const float* fsrc = (const float*)filt;
        #pragma unroll
        for (int i = 0; i < 4; i++) {
            int flat = i * 256 + t;
            sF[flat >> 6][flat & 63] = fsrc[flat];
        }
        if (t < 64) sB[t] = ((const float*)bias)[t];
    }
    __syncthreads();

    const int ty = t >> 4;
    const int tc = t & 15;

    float acc[4][4];
    {
        const float4 bv = *(const float4*)&sB[tc * 4];
        #pragma unroll
        for (int yi = 0; yi < 4; yi++) {
            acc[yi][0] = bv.x; acc[yi][1] = bv.y;
            acc[yi][2] = bv.z; acc[yi][3] = bv.w;
        }
    }

    #pragma unroll
    for (int p = 0; p < 4; p++) {
        float4 rin[4], rf[4];
        #pragma unroll
        for (int yi = 0; yi < 4; yi++)
            rin[yi] = *(const float4*)&sIn[p][ty * 16 + yi * 4];
        #pragma unroll
        for (int q = 0; q < 4; q++)
            rf[q] = *(const float4*)&sF[p * 4 + q][tc * 4];
        #pragma unroll
        for (int yi = 0; yi < 4; yi++) {
            #pragma unroll
            for (int q = 0; q < 4; q++) {
                const float a = ((const float*)&rin[yi])[q];
                acc[yi][0] = fmaf(a, rf[q].x, acc[yi][0]);
                acc[yi][1] = fmaf(a, rf[q].y, acc[yi][1]);
                acc[yi][2] = fmaf(a, rf[q].z, acc[yi][2]);
                acc[yi][3] = fmaf(a, rf[q].w, acc[yi][3]);
            }
        }
    }

    ushort_t* dst = (ushort_t*)(x0 + ((size_t)bl * 64 + X) * 64 * 64);
    #pragma unroll
    for (int yi = 0; yi < 4; yi++) {
        uint2 pk;
        pk.x = (uint32_t)f2bf(fmaxf(acc[yi][0], 0.f))
             | ((uint32_t)f2bf(fmaxf(acc[yi][1], 0.f)) << 16);
        pk.y = (uint32_t)f2bf(fmaxf(acc[yi][2], 0.f))
             | ((uint32_t)f2bf(fmaxf(acc[yi][3], 0.f)) << 16);
        *(uint2*)(dst + (size_t)(ty * 4 + yi) * 64 + tc * 4) = pk;
    }
}

// ---------------------------------------------------------------------------
// Repeat level (used for L1), verified rounds 4-8: block = (parent site, h,
// w, mtile of 64), wave = child; A fetched once for the 4 children.
// ---------------------------------------------------------------------------
__global__ __launch_bounds__(256) void k_level4(
    const __hip_bfloat16* __restrict__ xin,
    const ushort_t* __restrict__ wbuf,
    const float* __restrict__ bbuf,
    __hip_bfloat16* __restrict__ xout,
    int Nv_out, int HW, int Bc, int mtiles)
{
    __shared__ ushort_t smem[20480];
    __shared__ float sBias[4][64];
    ushort_t* sA = smem;
    ushort_t* sB = smem + 4096;

    int idx = blockIdx.x;
    const int mt = idx % mtiles; idx /= mtiles;
    const int w  = idx % HW; idx /= HW;
    const int h  = idx % HW; idx /= HW;
    const int Nv_in = Nv_out >> 1;
    const int vp = idx % Nv_in;
    const int up = idx / Nv_in;

    const int t = threadIdx.x;
    const int wave = t >> 6, lane = t & 63;
    const int lm = lane & 15, lq = lane >> 4;

    {
        const int ct = t >> 6, o = t & 63;
        const int so_t = (2 * up + (ct >> 1)) * Nv_out + (2 * vp + (ct & 1));
        sBias[ct][o] = bbuf[so_t * 64 + o];
    }

    const int so = (2 * up + (wave >> 1)) * Nv_out + (2 * vp + (wave & 1));
    const int H_in = HW * 2;
    const size_t bstride = (size_t)H_in * H_in * 64;
    const size_t siteb = (size_t)(up * Nv_in + vp) * Bc * bstride;
    const ushort_t* wsite = wbuf + (size_t)so * 4 * 4096;

    const f32x4 zero = {0.f, 0.f, 0.f, 0.f};
    f32x4 acc[4][4];
    #pragma unroll
    for (int i = 0; i < 4; i++)
        #pragma unroll
        for (int j = 0; j < 4; j++) acc[i][j] = zero;

    for (int tap = 0; tap < 4; tap++) {
        const int hi = 2 * h + (tap >> 1), wi = 2 * w + (tap & 1);
        const size_t tapoff = siteb + ((size_t)hi * H_in + wi) * 64;
        #pragma unroll
        for (int s2 = 0; s2 < 2; s2++) {
            const int s = wave * 2 + s2;
            const int ks = s >> 2, mh = s & 3;
            int b = mt * 64 + lm + mh * 16;
            if (b >= Bc) b = Bc - 1;
            gl_lds16(xin + tapoff + (size_t)b * bstride + ks * 32 + lq * 8,
                     &sA[s * 512]);
        }
        const ushort_t* wt = wsite + (size_t)tap * 4096;
        #pragma unroll
        for (int s = 0; s < 8; s++) {
            gl_lds16(wt + s * 512 + lane * 8, &sB[wave * 4096 + s * 512]);
        }
        __syncthreads();

        #pragma unroll
        for (int ks = 0; ks < 2; ks++) {
            short8 bf0 = *(const short8*)&sB[wave * 4096 + (ks * 4 + 0) * 512 + lane * 8];
            short8 bf1 = *(const short8*)&sB[wave * 4096 + (ks * 4 + 1) * 512 + lane * 8];
            short8 bf2 = *(const short8*)&sB[wave * 4096 + (ks * 4 + 2) * 512 + lane * 8];
            short8 bf3 = *(const short8*)&sB[wave * 4096 + (ks * 4 + 3) * 512 + lane * 8];
            #pragma unroll
            for (int fm = 0; fm < 4; fm++) {
                short8 a = *(const short8*)&sA[(ks * 4 + fm) * 512 + lane * 8];
                acc[fm][0] = __builtin_amdgcn_mfma_f32_16x16x32_bf16(a, bf0, acc[fm][0], 0, 0, 0);
                acc[fm][1] = __builtin_amdgcn_mfma_f32_16x16x32_bf16(a, bf1, acc[fm][1], 0, 0, 0);
                acc[fm][2] = __builtin_amdgcn_mfma_f32_16x16x32_bf16(a, bf2, acc[fm][2], 0, 0, 0);
                acc[fm][3] = __builtin_amdgcn_mfma_f32_16x16x32_bf16(a, bf3, acc[fm][3], 0, 0, 0);
            }
        }
        __syncthreads();
    }

    float bv[4];
    #pragma unroll
    for (int fn = 0; fn < 4; fn++) bv[fn] = sBias[wave][fn * 16 + lm];
    ushort_t* so_buf = smem + wave * 4352;
    #pragma unroll
    for (int fm = 0; fm < 4; fm++) {
        #pragma unroll
        for (int fn = 0; fn < 4; fn++) {
            #pragma unroll
            for (int r = 0; r < 4; r++) {
                const int row = fm * 16 + lq * 4 + r;
                so_buf[row * 68 + fn * 16 + lm] =
                    f2bf(fmaxf(acc[fm][fn][r] + bv[fn], 0.f));
            }
        }
    }
    __syncthreads();

    const size_t ostride = (size_t)HW * HW * 64;
    const size_t obase = (size_t)so * Bc * ostride + ((size_t)h * HW + w) * 64;
    #pragma unroll
    for (int i = 0; i < 8; i++) {
        const int task = i * 64 + lane;
        const int oct = task & 7, row = task >> 3;
        const int b = mt * 64 + row;
        if (b < Bc) {
            *(uint4*)(xout + obase + (size_t)b * ostride + oct * 8) =
                *(const uint4*)&so_buf[row * 68 + oct * 8];
        }
    }
}

// ---------------------------------------------------------------------------
// k_L23: fused L2 + L3. Block = (s2 L2-site, (h3,w3) L3 position, 32-batch
// mtile); sibling s2 blocks adjacent in dispatch (idx-minor) for cache reuse.
// Phase 1: wave = L2 position i in the 2x2 group (2h3+a, 2w3+b); M=32 GEMM
//   K=256 over taps; A staged wave-private (gl_lds16+waitcnt, k_f456 pattern);
//   B2 direct global->VGPR (L2-hot). bias2+relu -> mid slice (stride 72).
// Phase 2: wave = L3 child site of s2; taps = the 4 mid slices; B3 direct
//   global->VGPR; bias3+relu -> L3 out (64, Bc, 8,8,64).
// LDS ~35 KB -> 4 blocks/CU.
// ---------------------------------------------------------------------------
__global__ __launch_bounds__(256, 4) void k_L23(
    const __hip_bfloat16* __restrict__ xin,   // L1 out: (4, Bc, 32,32,64)
    const ushort_t* __restrict__ w2buf,       // wbuf + L2 offset
    const ushort_t* __restrict__ w3buf,       // wbuf + L3 offset
    const float* __restrict__ b2, const float* __restrict__ b3,
    __hip_bfloat16* __restrict__ xout,        // L3 out: (64, Bc, 8,8,64)
    int Bc, int mtiles)
{
    // smem: Aw 4 waves x 2048 | mid 4 slices x 2304  (17408 ushorts = 34 KB)
    __shared__ ushort_t smem[17408];
    __shared__ float sBias2[64];
    __shared__ float sBias3[4][64];

    int idx = blockIdx.x;
    const int sib = idx & 3; idx >>= 2;
    const int mt = idx % mtiles; idx /= mtiles;
    const int hw = idx & 63; idx >>= 6;
    const int s1 = idx;                        // 0..3
    const int h3 = hw >> 3, w3 = hw & 7;
    const int u2 = 2 * (s1 >> 1) + (sib >> 1);
    const int v2 = 2 * (s1 & 1) + (sib & 1);
    const int s2 = u2 * 4 + v2;

    const int t = threadIdx.x;
    const int wv = t >> 6, lane = t & 63;
    const int lm = lane & 15, lq = lane >> 4;

    {   // bias staging: sBias2 shared (needs barrier); sBias3 wave-private
        const int ct = t >> 6, o = t & 63;
        const int s3t = (2 * u2 + (ct >> 1)) * 8 + 2 * v2 + (ct & 1);
        sBias3[ct][o] = b3[s3t * 64 + o];
        if (t < 64) sBias2[t] = b2[s2 * 64 + t];
    }
    __syncthreads();

    const f32x4 zero = {0.f, 0.f, 0.f, 0.f};
    ushort_t* Aw = smem + wv * 2048;
    ushort_t* midw = smem + 8192 + wv * 2304;

    // ---------------- phase 1: L2, wave = position ----------------
    {
        const int h2 = 2 * h3 + (wv >> 1), w2p = 2 * w3 + (wv & 1);
        const size_t a1base = (size_t)s1 * Bc * 65536;   // 32*32*64
        const ushort_t* w2site = w2buf + (size_t)s2 * 16384;

        f32x4 acc[2][4];
        #pragma unroll
        for (int a_ = 0; a_ < 2; a_++)
            #pragma unroll
            for (int b_ = 0; b_ < 4; b_++) acc[a_][b_] = zero;

        for (int tap = 0; tap < 4; tap++) {
            const int hi = 2 * h2 + (tap >> 1), wi = 2 * w2p + (tap & 1);
            WAIT_LGKM0();   // prior tap's ds_reads of Aw retired (WAR)
            #pragma unroll
            for (int sl = 0; sl < 4; sl++) {     // sl = ks*2 + mh
                const int ks = sl >> 1, mh = sl & 1;
                int b = mt * 32 + mh * 16 + lm;
                if (b >= Bc) b = Bc - 1;
                gl_lds16(xin + a1base + (size_t)b * 65536
                             + ((size_t)hi * 32 + wi) * 64 + ks * 32 + lq * 8,
                         &Aw[sl * 512]);
            }
            short8 bfr[2][4];
            #pragma unroll
            for (int ks = 0; ks < 2; ks++)
                #pragma unroll
                for (int fn = 0; fn < 4; fn++)
                    bfr[ks][fn] = *(const short8*)(w2site + (size_t)tap * 4096
                                                   + (ks * 4 + fn) * 512 + lane * 8);
            WAIT_VM0();     // staged A (and B regs) visible
            #pragma unroll
            for (int ks = 0; ks < 2; ks++) {
                #pragma unroll
                for (int fm = 0; fm < 2; fm++) {
                    short8 a = *(const short8*)&Aw[(ks * 2 + fm) * 512 + lane * 8];
                    #pragma unroll
                    for (int fn = 0; fn < 4; fn++)
                        acc[fm][fn] = __builtin_amdgcn_mfma_f32_16x16x32_bf16(
                            a, bfr[ks][fn], acc[fm][fn], 0, 0, 0);
                }
            }
        }
        // epilogue 1: bias2 + relu -> own mid slice (A-operand layout, str 72)
        #pragma unroll
        for (int fm = 0; fm < 2; fm++) {
            #pragma unroll
            for (int fn = 0; fn < 4; fn++) {
                #pragma unroll
                for (int r = 0; r < 4; r++) {
                    const int m = fm * 16 + lq * 4 + r;
                    const int ch = fn * 16 + lm;
                    midw[m * 72 + ch] =
                        f2bf(fmaxf(acc[fm][fn][r] + sBias2[ch], 0.f));
                }
            }
        }
    }
    __syncthreads();   // mid visible to all waves

    // ---------------- phase 2: L3, wave = child site ----------------
    f32x4 acc3[2][4];
    #pragma unroll
    for (int a_ = 0; a_ < 2; a_++)
        #pragma unroll
        for (int b_ = 0; b_ < 4; b_++) acc3[a_][b_] = zero;

    const int u3 = 2 * u2 + (wv >> 1), v3 = 2 * v2 + (wv & 1);
    const int s3 = u3 * 8 + v3;
    {
        const ushort_t* w3site = w3buf + (size_t)s3 * 16384;
        for (int tap = 0; tap < 4; tap++) {
            const ushort_t* sl = smem + 8192 + tap * 2304;
            short8 bfr[2][4];
            #pragma unroll
            for (int ks = 0; ks < 2; ks++)
                #pragma unroll
                for (int fn = 0; fn < 4; fn++)
                    bfr[ks][fn] = *(const short8*)(w3site + (size_t)tap * 4096
                                                   + (ks * 4 + fn) * 512 + lane * 8);
            #pragma unroll
            for (int ks = 0; ks < 2; ks++) {
                short8 a0 = *(const short8*)&sl[lm * 72 + ks * 32 + lq * 8];
                short8 a1 = *(const short8*)&sl[(16 + lm) * 72 + ks * 32 + lq * 8];
                #pragma unroll
                for (int fn = 0; fn < 4; fn++) {
                    acc3[0][fn] = __builtin_amdgcn_mfma_f32_16x16x32_bf16(
                        a0, bfr[ks][fn], acc3[0][fn], 0, 0, 0);
                    acc3[1][fn] = __builtin_amdgcn_mfma_f32_16x16x32_bf16(
                        a1, bfr[ks][fn], acc3[1][fn], 0, 0, 0);
                }
            }
        }
    }
    __syncthreads();   // all waves done reading mid -> epi may overwrite

    // epilogue 2: bias3 + relu -> bf16 via own mid slice (stride 68), store
    {
        float bv[4];
        #pragma unroll
        for (int fn = 0; fn < 4; fn++) bv[fn] = sBias3[wv][fn * 16 + lm];
        ushort_t* epi = midw;              // 32 rows x 68 = 2176 <= 2304
        #pragma unroll
        for (int fm = 0; fm < 2; fm++) {
            #pragma unroll
            for (int fn = 0; fn < 4; fn++) {
                #pragma unroll
                for (int r = 0; r < 4; r++) {
                    const int row = fm * 16 + lq * 4 + r;
                    epi[row * 68 + fn * 16 + lm] =
                        f2bf(fmaxf(acc3[fm][fn][r] + bv[fn], 0.f));
                }
            }
        }
        const size_t obase = (size_t)s3 * Bc * 4096 + ((size_t)h3 * 8 + w3) * 64;
        #pragma unroll
        for (int i = 0; i < 4; i++) {
            const int task = i * 64 + lane;
            const int oc = task & 7, row = task >> 3;
            const int b = mt * 32 + row;
            if (b < Bc) {
                *(uint4*)(xout + obase + (size_t)b * 4096 + oc * 8) =
                    *(const uint4*)&epi[row * 68 + oc * 8];
            }
        }
    }
}

// ---------------------------------------------------------------------------
// k_f456: fused L4 + L5 + L6 + final (verified round 6).
// ---------------------------------------------------------------------------
__global__ __launch_bounds__(256, 1) void k_f456(
    const __hip_bfloat16* __restrict__ xin,   // L3 out: (64, Bc, 8,8,64)
    const ushort_t* __restrict__ w4, const ushort_t* __restrict__ w5,
    const ushort_t* __restrict__ w6, const ushort_t* __restrict__ wd,
    const float* __restrict__ b4, const float* __restrict__ b5,
    const float* __restrict__ b6,
    void* __restrict__ out, const int* __restrict__ flag,
    int Bc, int b_off, int mtiles)
{
    const int isbf = *flag;
    const int bx = blockIdx.x;
    const int mt = bx % mtiles;
    const int site = bx / mtiles;
    const int u = site >> 3, v = site & 7;

    __shared__ ushort_t smem[74752];
    __shared__ float sBias[192];

    const int t = threadIdx.x;
    const int wv = t >> 6, lane = t & 63;
    const int lm = lane & 15, lq = lane >> 4;

    if (t < 64) {
        sBias[t]       = b4[site * 64 + t];
        sBias[64 + t]  = b5[site * 64 + t];
        sBias[128 + t] = b6[site * 64 + t];
    }

    {
        const ushort_t* w4s = w4 + (size_t)site * 16384;
        const ushort_t* w5s = w5 + (size_t)site * 16384;
        #pragma unroll
        for (int s2 = 0; s2 < 8; s2++) {
            const int s = wv * 8 + s2;
            gl_lds16(w4s + s * 512 + lane * 8, &smem[s * 512]);
            gl_lds16(w5s + s * 512 + lane * 8, &smem[16384 + s * 512]);
        }
    }
    __syncthreads();

    const f32x4 zero = {0.f, 0.f, 0.f, 0.f};
    const int h5 = wv >> 1, w5p = wv & 1;
    ushort_t* mid1w = smem + 32768 + wv * 8448;
    ushort_t* Aw = smem + 66560 + wv * 2048;
    const size_t sb = (size_t)site * Bc;

    // phase 1: L4
    for (int i = 0; i < 4; i++) {
        const int h4 = 2 * h5 + (i >> 1), w4p = 2 * w5p + (i & 1);
        f32x4 acc[2][4];
        #pragma unroll
        for (int a_ = 0; a_ < 2; a_++)
            #pragma unroll
            for (int b_ = 0; b_ < 4; b_++) acc[a_][b_] = zero;

        for (int tap = 0; tap < 4; tap++) {
            const int h3 = 2 * h4 + (tap >> 1), w3 = 2 * w4p + (tap & 1);
            WAIT_LGKM0();
            #pragma unroll
            for (int sl = 0; sl < 4; sl++) {
                const int ks = sl >> 1, mh = sl & 1;
                int b = mt * 32 + mh * 16 + lm;
                if (b >= Bc) b = Bc - 1;
                gl_lds16(xin + (sb + b) * 4096 + (h3 * 8 + w3) * 64 + ks * 32 + lq * 8,
                         &Aw[sl * 512]);
            }
            WAIT_VM0();
            #pragma unroll
            for (int ks = 0; ks < 2; ks++) {
                #pragma unroll
                for (int fm = 0; fm < 2; fm++) {
                    short8 a = *(const short8*)&Aw[(ks * 2 + fm) * 512 + lane * 8];
                    #pragma unroll
                    for (int fn = 0; fn < 4; fn++) {
                        short8 bfr = *(const short8*)&smem[(tap * 8 + ks * 4 + fn) * 512 + lane * 8];
                        acc[fm][fn] = __builtin_amdgcn_mfma_f32_16x16x32_bf16(a, bfr, acc[fm][fn], 0, 0, 0);
                    }
                }
            }
        }
        #pragma unroll
        for (int fm = 0; fm < 2; fm++) {
            #pragma unroll
            for (int fn = 0; fn < 4; fn++) {
                #pragma unroll
                for (int r = 0; r < 4; r++) {
                    const int m = fm * 16 + lq * 4 + r;
                    const int ch = fn * 16 + lm;
                    mid1w[m * 264 + i * 64 + ch] =
                        f2bf(fmaxf(acc[fm][fn][r] + sBias[ch], 0.f));
                }
            }
        }
    }

    // phase 2: L5 (wave-private)
    {
        f32x4 acc2[2][4];
        #pragma unroll
        for (int a_ = 0; a_ < 2; a_++)
            #pragma unroll
            for (int b_ = 0; b_ < 4; b_++) acc2[a_][b_] = zero;

        #pragma unroll
        for (int i = 0; i < 4; i++) {
            #pragma unroll
            for (int ks = 0; ks < 2; ks++) {
                short8 a0 = *(const short8*)&mid1w[lm * 264 + i * 64 + ks * 32 + lq * 8];
                short8 a1 = *(const short8*)&mid1w[(16 + lm) * 264 + i * 64 + ks * 32 + lq * 8];
                #pragma unroll
                for (int fn = 0; fn < 4; fn++) {
                    short8 bfr = *(const short8*)&smem[16384 + (i * 8 + ks * 4 + fn) * 512 + lane * 8];
                    acc2[0][fn] = __builtin_amdgcn_mfma_f32_16x16x32_bf16(a0, bfr, acc2[0][fn], 0, 0, 0);
                    acc2[1][fn] = __builtin_amdgcn_mfma_f32_16x16x32_bf16(a1, bfr, acc2[1][fn], 0, 0, 0);
                }
            }
        }
        #pragma unroll
        for (int fm = 0; fm < 2; fm++) {
            #pragma unroll
            for (int fn = 0; fn < 4; fn++) {
                #pragma unroll
                for (int r = 0; r < 4; r++) {
                    const int m = fm * 16 + lq * 4 + r;
                    const int ch = fn * 16 + lm;
                    mid1w[m * 72 + ch] =
                        f2bf(fmaxf(acc2[fm][fn][r] + sBias[64 + ch], 0.f));
                }
            }
        }
    }
    __syncthreads();

    {
        const ushort_t* w6s = w6 + (size_t)site * 16384;
        const ushort_t* wds = wd + (size_t)site * 8192;
        #pragma unroll
        for (int s2 = 0; s2 < 8; s2++) {
            const int s = wv * 8 + s2;
            gl_lds16(w6s + s * 512 + lane * 8, &smem[s * 512]);
        }
        #pragma unroll
        for (int s2 = 0; s2 < 4; s2++) {
            const int s = wv * 4 + s2;
            gl_lds16(wds + s * 512 + lane * 8, &smem[16384 + s * 512]);
        }
    }
    __syncthreads();

    // phase 3: L6
    {
        f32x4 acc3[2];
        acc3[0] = zero; acc3[1] = zero;
        #pragma unroll
        for (int tap = 0; tap < 4; tap++) {
            const ushort_t* sl = smem + 32768 + tap * 8448;
            #pragma unroll
            for (int ks = 0; ks < 2; ks++) {
                short8 a0 = *(const short8*)&sl[lm * 72 + ks * 32 + lq * 8];
                short8 a1 = *(const short8*)&sl[(16 + lm) * 72 + ks * 32 + lq * 8];
                short8 bfr = *(const short8*)&smem[(tap * 8 + ks * 4 + wv) * 512 + lane * 8];
                acc3[0] = __builtin_amdgcn_mfma_f32_16x16x32_bf16(a0, bfr, acc3[0], 0, 0, 0);
                acc3[1] = __builtin_amdgcn_mfma_f32_16x16x32_bf16(a1, bfr, acc3[1], 0, 0, 0);
            }
        }
        ushort_t* mid3 = smem + 66560;
        #pragma unroll
        for (int fm = 0; fm < 2; fm++) {
            #pragma unroll
            for (int r = 0; r < 4; r++) {
                const int m = fm * 16 + lq * 4 + r;
                const int ch = wv * 16 + lm;
                mid3[m * 72 + ch] =
                    f2bf(fmaxf(acc3[fm][r] + sBias[128 + ch], 0.f));
            }
        }
    }
    __syncthreads();

    // phase 4: final projection
    {
        const ushort_t* mid3 = smem + 66560;
        f32x4 acc4[2][2];
        acc4[0][0] = zero; acc4[0][1] = zero; acc4[1][0] = zero; acc4[1][1] = zero;
        #pragma unroll
        for (int ks = 0; ks < 2; ks++) {
            short8 a0 = *(const short8*)&mid3[lm * 72 + ks * 32 + lq * 8];
            short8 a1 = *(const short8*)&mid3[(16 + lm) * 72 + ks * 32 + lq * 8];
            #pragma unroll
            for (int n2 = 0; n2 < 2; n2++) {
                const int nh = 2 * wv + n2;
                short8 bfr = *(const short8*)&smem[16384 + (ks * 8 + nh) * 512 + lane * 8];
                acc4[0][n2] = __builtin_amdgcn_mfma_f32_16x16x32_bf16(a0, bfr, acc4[0][n2], 0, 0, 0);
                acc4[1][n2] = __builtin_amdgcn_mfma_f32_16x16x32_bf16(a1, bfr, acc4[1][n2], 0, 0, 0);
            }
        }
        #pragma unroll
        for (int fm = 0; fm < 2; fm++) {
            #pragma unroll
            for (int n2 = 0; n2 < 2; n2++) {
                const int n = (2 * wv + n2) * 16 + lm;
                const int rr = n >> 6, ou = (n >> 3) & 7, ov = n & 7;
                const size_t obase =
                    (((size_t)(u * 8 + ou)) * 64 + (v * 8 + ov)) * 2 + rr;
                #pragma unroll
                for (int reg = 0; reg < 4; reg++) {
                    const int brow = mt * 32 + fm * 16 + lq * 4 + reg;
                    if (brow < Bc) {
                        const size_t oidx = obase + (size_t)(b_off + brow) * 8192;
                        if (isbf) ((__hip_bfloat16*)out)[oidx] =
                            __float2bfloat16(acc4[fm][n2][reg]);
                        else ((float*)out)[oidx] = acc4[fm][n2][reg];
                    }
                }
            }
        }
    }
}

// ---------------------------------------------------------------------------
extern "C" void kernel_launch(void* const* d_in, const int* in_sizes, int n_in,
                              void* d_out, int out_size, void* d_ws, size_t ws_size,
                              hipStream_t stream)
{
    (void)in_sizes; (void)n_in; (void)out_size;

    const void* in_data = d_in[0];
    const void* filt    = d_in[1];
    const void* bias0   = d_in[2];
    const void* fl[7];
    const void* bl[7];
    for (int l = 1; l <= 6; l++) {
        fl[l] = d_in[1 + 2 * l];
        bl[l] = d_in[2 + 2 * l];
    }
    const void* Wd = d_in[15];

    const int Bfull = 128;
    const size_t perB = (size_t)64 * 64 * 64;

    const size_t wbufBytes  = 565248ull * 16;
    const size_t wdbufBytes = 65536ull * 16;
    const size_t bbufBytes  = 17664ull * 4;
    const size_t headBytes  = 256 + wbufBytes + wdbufBytes + bbufBytes;

    const size_t avail = ws_size > headBytes ? ws_size - headBytes : 0;
    int Bc = 0;
    for (int c = 128; c >= 1; c >>= 1) {
        if ((size_t)2 * c * perB * sizeof(__hip_bfloat16) <= avail) { Bc = c; break; }
    }
    if (Bc == 0) return;

    int* flag = (int*)d_ws;
    ushort_t* wbuf  = (ushort_t*)((char*)d_ws + 256);
    ushort_t* wdbuf = (ushort_t*)((char*)d_ws + 256 + wbufBytes);
    float* bbuf = (float*)((char*)d_ws + 256 + wbufBytes + wdbufBytes);
    __hip_bfloat16* bufA = (__hip_bfloat16*)((char*)d_ws + headBytes);
    __hip_bfloat16* bufB = bufA + (size_t)Bc * perB;

    static const size_t w_off[7] = {0, 0, 65536, 327680, 1376256, 2424832, 3473408};
    static const int    b_off_tab[7] = {0, 0, 256, 1280, 5376, 9472, 13568};

    k_prep<<<dim3(2533), 256, 0, stream>>>(
        (const uint32_t*)in_data,
        fl[1], fl[2], fl[3], fl[4], fl[5], fl[6], Wd,
        bl[1], bl[2], bl[3], bl[4], bl[5], bl[6],
        wbuf, wdbuf, bbuf, flag);

    const int mt4 = (Bc + 63) / 64;
    const int mt32 = (Bc + 31) / 32;

    for (int b_off = 0; b_off < Bfull; b_off += Bc) {
        // stage0 -> bufA (x0: (Bc,64,64,64))
        k_stage0<<<dim3(Bc * 64), 256, 0, stream>>>(in_data, filt, bias0, bufA, flag, b_off);

        // L1 -> bufB ((4,Bc,32,32,64))
        k_level4<<<dim3(32 * 32 * mt4), 256, 0, stream>>>(
            bufA, wbuf + w_off[1], bbuf + b_off_tab[1], bufB, 2, 32, Bc, mt4);

        // fused L2+L3 -> bufA ((64,Bc,8,8,64))
        k_L23<<<dim3(1024 * mt32), 256, 0, stream>>>(
            bufB, wbuf + w_off[2], wbuf + w_off[3],
            bbuf + b_off_tab[2], bbuf + b_off_tab[3], bufA, Bc, mt32);

        // fused L4+L5+L6+final -> d_out
        k_f456<<<dim3(64 * mt32), 256, 0, stream>>>(bufA,
            wbuf + w_off[4], wbuf + w_off[5], wbuf + w_off[6], wdbuf,
            bbuf + b_off_tab[4], bbuf + b_off_tab[5], bbuf + b_off_tab[6],
            d_out, flag, Bc, b_off, mt32);
    }
}

// Round 10
// 258.133 us; speedup vs baseline: 1.0520x; 1.0047x over previous
//
#include <hip/hip_runtime.h>
#include <hip/hip_bf16.h>
#include <cstdint>
#include <cstddef>

// ButterflyLayer2D on MI355X.
// Round-6 skeleton (best): stage0 -> k_level4 (L1,L2,L3) -> k_f456.
// Round-10 k_level4: B weights direct global->VGPR (L2-hot), A tile
// double-buffered -> 1 barrier/tap.
// Weights pre-transposed once into MFMA B-fragment layout (bf16) in d_ws.

typedef __attribute__((ext_vector_type(8))) short short8;
typedef __attribute__((ext_vector_type(4))) float f32x4;
typedef unsigned short ushort_t;

static __device__ __forceinline__ float b2f(const __hip_bfloat16 x) {
    return __bfloat162float(x);
}
static __device__ __forceinline__ ushort_t f2bf(float x) {
    __hip_bfloat16 h = __float2bfloat16(x);
    ushort_t u;
    __builtin_memcpy(&u, &h, 2);
    return u;
}
static __device__ __forceinline__ void gl_lds16(const void* g, void* l) {
    __builtin_amdgcn_global_load_lds(
        (const __attribute__((address_space(1))) void*)g,
        (__attribute__((address_space(3))) void*)l, 16, 0, 0);
}
// gfx9 waitcnt encodings: lgkmcnt(0) only / vmcnt(0) only
#define WAIT_LGKM0() __builtin_amdgcn_s_waitcnt(0xC07F)
#define WAIT_VM0()   __builtin_amdgcn_s_waitcnt(0x0F70)

// ---------------------------------------------------------------------------
// k_prep: merged dtype-detect + weight transpose + bias convert (verified r6).
// gid ranges: [0,565248) level weights; [565248,630784) Wd; [630784,648448) bias.
// ---------------------------------------------------------------------------
__global__ __launch_bounds__(256) void k_prep(
    const uint32_t* __restrict__ in_words,
    const void* f1, const void* f2, const void* f3,
    const void* f4, const void* f5, const void* f6, const void* wdsrc,
    const void* b1, const void* b2, const void* b3,
    const void* b4, const void* b5, const void* b6,
    ushort_t* __restrict__ wbuf, ushort_t* __restrict__ wdbuf,
    float* __restrict__ bbuf, int* __restrict__ flag)
{
    __shared__ int sflag;
    const int t = threadIdx.x;
    if (t < 64) {
        const float v = __uint_as_float(in_words[t]);
        const bool plaus = (v == 0.0f) || (fabsf(v) > 1e-8f && fabsf(v) < 1e4f);
        const unsigned long long m = __ballot(plaus);
        if (t == 0) sflag = (__popcll(m) >= 48) ? 0 : 1;
    }
    __syncthreads();
    const int isbf = sflag;
    const int gid = blockIdx.x * 256 + t;
    if (blockIdx.x == 0 && t == 0) *flag = isbf;

    if (gid >= 648448) return;
    if (gid >= 630784) {
        const int bg = gid - 630784;
        const void* src; int base;
        if      (bg <   256) { src = b1; base = 0;     }
        else if (bg <  1280) { src = b2; base = 256;   }
        else if (bg <  5376) { src = b3; base = 1280;  }
        else if (bg <  9472) { src = b4; base = 5376;  }
        else if (bg < 13568) { src = b5; base = 9472;  }
        else                 { src = b6; base = 13568; }
        const int local = bg - base;
        bbuf[bg] = isbf ? b2f(((const __hip_bfloat16*)src)[local])
                        : ((const float*)src)[local];
        return;
    }
    if (gid >= 565248) {
        const int local = gid - 565248;
        const int lane = local & 63;
        const int slot = (local >> 6) & 15;
        const int site = local >> 10;
        const int ks2 = slot >> 3, nh = slot & 7, q = lane >> 4;
        const int n = nh * 16 + (lane & 15);
        const int r = n >> 6, kk = n & 63;
        const int cbase = ks2 * 32 + q * 8;
        ushort_t pk[8];
        if (isbf) {
            const ushort_t* s = (const ushort_t*)wdsrc;
            #pragma unroll
            for (int j = 0; j < 8; j++)
                pk[j] = s[(((size_t)(site * 2 + r) * 64 + cbase + j) * 64) + kk];
        } else {
            const float* s = (const float*)wdsrc;
            #pragma unroll
            for (int j = 0; j < 8; j++)
                pk[j] = f2bf(s[(((size_t)(site * 2 + r) * 64 + cbase + j) * 64) + kk]);
        }
        *(uint4*)&wdbuf[(size_t)local * 8] = *(uint4*)pk;
        return;
    }
    const void* fsrc; int base;
    if      (gid <   8192) { fsrc = f1; base = 0;      }
    else if (gid <  40960) { fsrc = f2; base = 8192;   }
    else if (gid < 172032) { fsrc = f3; base = 40960;  }
    else if (gid < 303104) { fsrc = f4; base = 172032; }
    else if (gid < 434176) { fsrc = f5; base = 303104; }
    else                   { fsrc = f6; base = 434176; }
    const int local = gid - base;
    const int lane = local & 63;
    const int slot = (local >> 6) & 7;
    const int sitetap = local >> 9;
    const int ks = slot >> 2, nh = slot & 3, q = lane >> 4;
    const int n = (lane & 15) + nh * 16;
    const int kbase = ks * 32 + q * 8;
    ushort_t pk[8];
    if (isbf) {
        const ushort_t* s = (const ushort_t*)fsrc + (size_t)sitetap * 4096;
        #pragma unroll
        for (int j = 0; j < 8; j++) pk[j] = s[(kbase + j) * 64 + n];
    } else {
        const float* s = (const float*)fsrc + (size_t)sitetap * 4096;
        #pragma unroll
        for (int j = 0; j < 8; j++) pk[j] = f2bf(s[(kbase + j) * 64 + n]);
    }
    *(uint4*)&wbuf[(size_t)gid * 8] = *(uint4*)pk;
}

// ---------------------------------------------------------------------------
// Stage 0 (verified rounds 5-9): patch-embed, register-tiled, bf16 out.
// ---------------------------------------------------------------------------
__global__ __launch_bounds__(256) void k_stage0(
    const void* __restrict__ in_data, const void* __restrict__ filt,
    const void* __restrict__ bias, __hip_bfloat16* __restrict__ x0,
    const int* __restrict__ flag, int b_off)
{
    const int isbf = *flag;
    const int blk = blockIdx.x;
    const int X  = blk & 63;
    const int bl = blk >> 6;
    const int bg = bl + b_off;

    __shared__ float sIn[4][256];
    __shared__ float sF[16][64];
    __shared__ float sB[64];

    const int t = threadIdx.x;
    const size_t srow = ((size_t)bg * 256 + (size_t)X * 4) * 256;

    if (isbf) {
        const __hip_bfloat16* src = (const __hip_bfloat16*)in_data + srow;
        #pragma unroll
        for (int i = 0; i < 4; i++) {
            int flat = i * 256 + t;
            int p = flat >> 8, col = flat & 255;
            sIn[p][col] = b2f(src[(size_t)p * 256 + col]);
        }
        const __hip_bfloat16* fsrc = (const __hip_bfloat16*)filt;
        #pragma unroll
        for (int i = 0; i < 4; i++) {
            int flat = i * 256 + t;
            sF[flat >> 6][flat & 63] = b2f(fsrc[flat]);
        }
        if (t < 64) sB[t] = b2f(((const __hip_bfloat16*)bias)[t]);
    } else {
        const float* src = (const float*)in_data + srow;
        const int p = t >> 6, c4 = (t & 63) * 4;
        *(float4*)&sIn[p][c4] = *(const float4*)(src + (size_t)p * 256 + c4);
        const float* fsrc = (const float*)filt;
        #pragma unroll
        for (int i = 0; i < 4; i++) {
            int flat = i * 256 + t;
            sF[flat >> 6][flat & 63] = fsrc[flat];
        }
        if (t < 64) sB[t] = ((const float*)bias)[t];
    }
    __syncthreads();

    const int ty = t >> 4;
    const int tc = t & 15;

    float acc[4][4];
    {
        const float4 bv = *(const float4*)&sB[tc * 4];
        #pragma unroll
        for (int yi = 0; yi < 4; yi++) {
            acc[yi][0] = bv.x; acc[yi][1] = bv.y;
            acc[yi][2] = bv.z; acc[yi][3] = bv.w;
        }
    }

    #pragma unroll
    for (int p = 0; p < 4; p++) {
        float4 rin[4], rf[4];
        #pragma unroll
        for (int yi = 0; yi < 4; yi++)
            rin[yi] = *(const float4*)&sIn[p][ty * 16 + yi * 4];
        #pragma unroll
        for (int q = 0; q < 4; q++)
            rf[q] = *(const float4*)&sF[p * 4 + q][tc * 4];
        #pragma unroll
        for (int yi = 0; yi < 4; yi++) {
            #pragma unroll
            for (int q = 0; q < 4; q++) {
                const float a = ((const float*)&rin[yi])[q];
                acc[yi][0] = fmaf(a, rf[q].x, acc[yi][0]);
                acc[yi][1] = fmaf(a, rf[q].y, acc[yi][1]);
                acc[yi][2] = fmaf(a, rf[q].z, acc[yi][2]);
                acc[yi][3] = fmaf(a, rf[q].w, acc[yi][3]);
            }
        }
    }

    ushort_t* dst = (ushort_t*)(x0 + ((size_t)bl * 64 + X) * 64 * 64);
    #pragma unroll
    for (int yi = 0; yi < 4; yi++) {
        uint2 pk;
        pk.x = (uint32_t)f2bf(fmaxf(acc[yi][0], 0.f))
             | ((uint32_t)f2bf(fmaxf(acc[yi][1], 0.f)) << 16);
        pk.y = (uint32_t)f2bf(fmaxf(acc[yi][2], 0.f))
             | ((uint32_t)f2bf(fmaxf(acc[yi][3], 0.f)) << 16);
        *(uint2*)(dst + (size_t)(ty * 4 + yi) * 64 + tc * 4) = pk;
    }
}

// ---------------------------------------------------------------------------
// Repeat level (L1-L3), round-10: block = (parent site, h, w, mtile of 64),
// wave = child; A fetched once for the 4 children, DOUBLE-BUFFERED (1 barrier
// per tap); B weights direct global->VGPR (L2-hot, coalesced 16B/lane).
// ---------------------------------------------------------------------------
__global__ __launch_bounds__(256) void k_level4(
    const __hip_bfloat16* __restrict__ xin,
    const ushort_t* __restrict__ wbuf,   // level offset applied by host
    const float* __restrict__ bbuf,      // level offset applied by host
    __hip_bfloat16* __restrict__ xout,
    int Nv_out, int HW, int Bc, int mtiles)
{
    // smem: A dbuf 2 x 4096 ushorts [0,8192) ; epilogue 4 waves x 4352 [0,17408)
    __shared__ ushort_t smem[17408];
    __shared__ float sBias[4][64];

    int idx = blockIdx.x;
    const int mt = idx % mtiles; idx /= mtiles;
    const int w  = idx % HW; idx /= HW;
    const int h  = idx % HW; idx /= HW;
    const int Nv_in = Nv_out >> 1;
    const int vp = idx % Nv_in;
    const int up = idx / Nv_in;

    const int t = threadIdx.x;
    const int wave = t >> 6, lane = t & 63;
    const int lm = lane & 15, lq = lane >> 4;

    {
        const int ct = t >> 6, o = t & 63;
        const int so_t = (2 * up + (ct >> 1)) * Nv_out + (2 * vp + (ct & 1));
        sBias[ct][o] = bbuf[so_t * 64 + o];
    }

    const int so = (2 * up + (wave >> 1)) * Nv_out + (2 * vp + (wave & 1));
    const int H_in = HW * 2;
    const size_t bstride = (size_t)H_in * H_in * 64;
    const size_t siteb = (size_t)(up * Nv_in + vp) * Bc * bstride;
    const ushort_t* wsite = wbuf + (size_t)so * 4 * 4096;

    // A-row indices for this wave's 2 staged slots (s = wave*2 + s2)
    int arow[2];
    #pragma unroll
    for (int s2 = 0; s2 < 2; s2++) {
        const int s = wave * 2 + s2;
        int b = mt * 64 + lm + (s & 3) * 16;
        if (b >= Bc) b = Bc - 1;
        arow[s2] = b;
    }

    const f32x4 zero = {0.f, 0.f, 0.f, 0.f};
    f32x4 acc[4][4];
    #pragma unroll
    for (int i = 0; i < 4; i++)
        #pragma unroll
        for (int j = 0; j < 4; j++) acc[i][j] = zero;

    // stage tap 0 -> buf 0
    {
        const size_t tapoff = siteb + ((size_t)(2 * h) * H_in + (2 * w)) * 64;
        #pragma unroll
        for (int s2 = 0; s2 < 2; s2++) {
            const int s = wave * 2 + s2;
            gl_lds16(xin + tapoff + (size_t)arow[s2] * bstride + (s >> 2) * 32 + lq * 8,
                     &smem[s * 512]);
        }
    }
    __syncthreads();

    int cur = 0;
    for (int tap = 0; tap < 4; tap++) {
        // B for this tap -> regs (issued BEFORE next-tap staging so the
        // compiler's waitcnt for bfr doesn't drain the stage queue)
        short8 bfr[2][4];
        #pragma unroll
        for (int ks = 0; ks < 2; ks++)
            #pragma unroll
            for (int fn = 0; fn < 4; fn++)
                bfr[ks][fn] = *(const short8*)(wsite + (size_t)tap * 4096
                                               + (ks * 4 + fn) * 512 + lane * 8);
        if (tap < 3) {
            const int nt = tap + 1;
            const int hi = 2 * h + (nt >> 1), wi = 2 * w + (nt & 1);
            const size_t tapoff = siteb + ((size_t)hi * H_in + wi) * 64;
            #pragma unroll
            for (int s2 = 0; s2 < 2; s2++) {
                const int s = wave * 2 + s2;
                gl_lds16(xin + tapoff + (size_t)arow[s2] * bstride + (s >> 2) * 32 + lq * 8,
                         &smem[(cur ^ 1) * 4096 + s * 512]);
            }
        }

        #pragma unroll
        for (int ks = 0; ks < 2; ks++) {
            #pragma unroll
            for (int fm = 0; fm < 4; fm++) {
                short8 a = *(const short8*)&smem[cur * 4096 + (ks * 4 + fm) * 512 + lane * 8];
                acc[fm][0] = __builtin_amdgcn_mfma_f32_16x16x32_bf16(a, bfr[ks][0], acc[fm][0], 0, 0, 0);
                acc[fm][1] = __builtin_amdgcn_mfma_f32_16x16x32_bf16(a, bfr[ks][1], acc[fm][1], 0, 0, 0);
                acc[fm][2] = __builtin_amdgcn_mfma_f32_16x16x32_bf16(a, bfr[ks][2], acc[fm][2], 0, 0, 0);
                acc[fm][3] = __builtin_amdgcn_mfma_f32_16x16x32_bf16(a, bfr[ks][3], acc[fm][3], 0, 0, 0);
            }
        }
        __syncthreads();   // drains this wave's ds_reads + all waves' staging
        cur ^= 1;
    }

    // epilogue: bias + relu -> bf16 tile (per-wave region), vector store
    float bv[4];
    #pragma unroll
    for (int fn = 0; fn < 4; fn++) bv[fn] = sBias[wave][fn * 16 + lm];
    ushort_t* so_buf = smem + wave * 4352;
    #pragma unroll
    for (int fm = 0; fm < 4; fm++) {
        #pragma unroll
        for (int fn = 0; fn < 4; fn++) {
            #pragma unroll
            for (int r = 0; r < 4; r++) {
                const int row = fm * 16 + lq * 4 + r;
                so_buf[row * 68 + fn * 16 + lm] =
                    f2bf(fmaxf(acc[fm][fn][r] + bv[fn], 0.f));
            }
        }
    }
    __syncthreads();

    const size_t ostride = (size_t)HW * HW * 64;
    const size_t obase = (size_t)so * Bc * ostride + ((size_t)h * HW + w) * 64;
    #pragma unroll
    for (int i = 0; i < 8; i++) {
        const int task = i * 64 + lane;
        const int oct = task & 7, row = task >> 3;
        const int b = mt * 64 + row;
        if (b < Bc) {
            *(uint4*)(xout + obase + (size_t)b * ostride + oct * 8) =
                *(const uint4*)&so_buf[row * 68 + oct * 8];
        }
    }
}

// ---------------------------------------------------------------------------
// k_f456: fused L4 + L5 + L6 + final (verified round 6).
// ---------------------------------------------------------------------------
__global__ __launch_bounds__(256, 1) void k_f456(
    const __hip_bfloat16* __restrict__ xin,   // L3 out: (64, Bc, 8,8,64)
    const ushort_t* __restrict__ w4, const ushort_t* __restrict__ w5,
    const ushort_t* __restrict__ w6, const ushort_t* __restrict__ wd,
    const float* __restrict__ b4, const float* __restrict__ b5,
    const float* __restrict__ b6,
    void* __restrict__ out, const int* __restrict__ flag,
    int Bc, int b_off, int mtiles)
{
    const int isbf = *flag;
    const int bx = blockIdx.x;
    const int mt = bx % mtiles;
    const int site = bx / mtiles;
    const int u = site >> 3, v = site & 7;

    __shared__ ushort_t smem[74752];
    __shared__ float sBias[192];

    const int t = threadIdx.x;
    const int wv = t >> 6, lane = t & 63;
    const int lm = lane & 15, lq = lane >> 4;

    if (t < 64) {
        sBias[t]       = b4[site * 64 + t];
        sBias[64 + t]  = b5[site * 64 + t];
        sBias[128 + t] = b6[site * 64 + t];
    }

    {
        const ushort_t* w4s = w4 + (size_t)site * 16384;
        const ushort_t* w5s = w5 + (size_t)site * 16384;
        #pragma unroll
        for (int s2 = 0; s2 < 8; s2++) {
            const int s = wv * 8 + s2;
            gl_lds16(w4s + s * 512 + lane * 8, &smem[s * 512]);
            gl_lds16(w5s + s * 512 + lane * 8, &smem[16384 + s * 512]);
        }
    }
    __syncthreads();

    const f32x4 zero = {0.f, 0.f, 0.f, 0.f};
    const int h5 = wv >> 1, w5p = wv & 1;
    ushort_t* mid1w = smem + 32768 + wv * 8448;
    ushort_t* Aw = smem + 66560 + wv * 2048;
    const size_t sb = (size_t)site * Bc;

    // phase 1: L4
    for (int i = 0; i < 4; i++) {
        const int h4 = 2 * h5 + (i >> 1), w4p = 2 * w5p + (i & 1);
        f32x4 acc[2][4];
        #pragma unroll
        for (int a_ = 0; a_ < 2; a_++)
            #pragma unroll
            for (int b_ = 0; b_ < 4; b_++) acc[a_][b_] = zero;

        for (int tap = 0; tap < 4; tap++) {
            const int h3 = 2 * h4 + (tap >> 1), w3 = 2 * w4p + (tap & 1);
            WAIT_LGKM0();
            #pragma unroll
            for (int sl = 0; sl < 4; sl++) {
                const int ks = sl >> 1, mh = sl & 1;
                int b = mt * 32 + mh * 16 + lm;
                if (b >= Bc) b = Bc - 1;
                gl_lds16(xin + (sb + b) * 4096 + (h3 * 8 + w3) * 64 + ks * 32 + lq * 8,
                         &Aw[sl * 512]);
            }
            WAIT_VM0();
            #pragma unroll
            for (int ks = 0; ks < 2; ks++) {
                #pragma unroll
                for (int fm = 0; fm < 2; fm++) {
                    short8 a = *(const short8*)&Aw[(ks * 2 + fm) * 512 + lane * 8];
                    #pragma unroll
                    for (int fn = 0; fn < 4; fn++) {
                        short8 bfr = *(const short8*)&smem[(tap * 8 + ks * 4 + fn) * 512 + lane * 8];
                        acc[fm][fn] = __builtin_amdgcn_mfma_f32_16x16x32_bf16(a, bfr, acc[fm][fn], 0, 0, 0);
                    }
                }
            }
        }
        #pragma unroll
        for (int fm = 0; fm < 2; fm++) {
            #pragma unroll
            for (int fn = 0; fn < 4; fn++) {
                #pragma unroll
                for (int r = 0; r < 4; r++) {
                    const int m = fm * 16 + lq * 4 + r;
                    const int ch = fn * 16 + lm;
                    mid1w[m * 264 + i * 64 + ch] =
                        f2bf(fmaxf(acc[fm][fn][r] + sBias[ch], 0.f));
                }
            }
        }
    }

    // phase 2: L5 (wave-private)
    {
        f32x4 acc2[2][4];
        #pragma unroll
        for (int a_ = 0; a_ < 2; a_++)
            #pragma unroll
            for (int b_ = 0; b_ < 4; b_++) acc2[a_][b_] = zero;

        #pragma unroll
        for (int i = 0; i < 4; i++) {
            #pragma unroll
            for (int ks = 0; ks < 2; ks++) {
                short8 a0 = *(const short8*)&mid1w[lm * 264 + i * 64 + ks * 32 + lq * 8];
                short8 a1 = *(const short8*)&mid1w[(16 + lm) * 264 + i * 64 + ks * 32 + lq * 8];
                #pragma unroll
                for (int fn = 0; fn < 4; fn++) {
                    short8 bfr = *(const short8*)&smem[16384 + (i * 8 + ks * 4 + fn) * 512 + lane * 8];
                    acc2[0][fn] = __builtin_amdgcn_mfma_f32_16x16x32_bf16(a0, bfr, acc2[0][fn], 0, 0, 0);
                    acc2[1][fn] = __builtin_amdgcn_mfma_f32_16x16x32_bf16(a1, bfr, acc2[1][fn], 0, 0, 0);
                }
            }
        }
        #pragma unroll
        for (int fm = 0; fm < 2; fm++) {
            #pragma unroll
            for (int fn = 0; fn < 4; fn++) {
                #pragma unroll
                for (int r = 0; r < 4; r++) {
                    const int m = fm * 16 + lq * 4 + r;
                    const int ch = fn * 16 + lm;
                    mid1w[m * 72 + ch] =
                        f2bf(fmaxf(acc2[fm][fn][r] + sBias[64 + ch], 0.f));
                }
            }
        }
    }
    __syncthreads();

    {
        const ushort_t* w6s = w6 + (size_t)site * 16384;
        const ushort_t* wds = wd + (size_t)site * 8192;
        #pragma unroll
        for (int s2 = 0; s2 < 8; s2++) {
            const int s = wv * 8 + s2;
            gl_lds16(w6s + s * 512 + lane * 8, &smem[s * 512]);
        }
        #pragma unroll
        for (int s2 = 0; s2 < 4; s2++) {
            const int s = wv * 4 + s2;
            gl_lds16(wds + s * 512 + lane * 8, &smem[16384 + s * 512]);
        }
    }
    __syncthreads();

    // phase 3: L6
    {
        f32x4 acc3[2];
        acc3[0] = zero; acc3[1] = zero;
        #pragma unroll
        for (int tap = 0; tap < 4; tap++) {
            const ushort_t* sl = smem + 32768 + tap * 8448;
            #pragma unroll
            for (int ks = 0; ks < 2; ks++) {
                short8 a0 = *(const short8*)&sl[lm * 72 + ks * 32 + lq * 8];
                short8 a1 = *(const short8*)&sl[(16 + lm) * 72 + ks * 32 + lq * 8];
                short8 bfr = *(const short8*)&smem[(tap * 8 + ks * 4 + wv) * 512 + lane * 8];
                acc3[0] = __builtin_amdgcn_mfma_f32_16x16x32_bf16(a0, bfr, acc3[0], 0, 0, 0);
                acc3[1] = __builtin_amdgcn_mfma_f32_16x16x32_bf16(a1, bfr, acc3[1], 0, 0, 0);
            }
        }
        ushort_t* mid3 = smem + 66560;
        #pragma unroll
        for (int fm = 0; fm < 2; fm++) {
            #pragma unroll
            for (int r = 0; r < 4; r++) {
                const int m = fm * 16 + lq * 4 + r;
                const int ch = wv * 16 + lm;
                mid3[m * 72 + ch] =
                    f2bf(fmaxf(acc3[fm][r] + sBias[128 + ch], 0.f));
            }
        }
    }
    __syncthreads();

    // phase 4: final projection
    {
        const ushort_t* mid3 = smem + 66560;
        f32x4 acc4[2][2];
        acc4[0][0] = zero; acc4[0][1] = zero; acc4[1][0] = zero; acc4[1][1] = zero;
        #pragma unroll
        for (int ks = 0; ks < 2; ks++) {
            short8 a0 = *(const short8*)&mid3[lm * 72 + ks * 32 + lq * 8];
            short8 a1 = *(const short8*)&mid3[(16 + lm) * 72 + ks * 32 + lq * 8];
            #pragma unroll
            for (int n2 = 0; n2 < 2; n2++) {
                const int nh = 2 * wv + n2;
                short8 bfr = *(const short8*)&smem[16384 + (ks * 8 + nh) * 512 + lane * 8];
                acc4[0][n2] = __builtin_amdgcn_mfma_f32_16x16x32_bf16(a0, bfr, acc4[0][n2], 0, 0, 0);
                acc4[1][n2] = __builtin_amdgcn_mfma_f32_16x16x32_bf16(a1, bfr, acc4[1][n2], 0, 0, 0);
            }
        }
        #pragma unroll
        for (int fm = 0; fm < 2; fm++) {
            #pragma unroll
            for (int n2 = 0; n2 < 2; n2++) {
                const int n = (2 * wv + n2) * 16 + lm;
                const int rr = n >> 6, ou = (n >> 3) & 7, ov = n & 7;
                const size_t obase =
                    (((size_t)(u * 8 + ou)) * 64 + (v * 8 + ov)) * 2 + rr;
                #pragma unroll
                for (int reg = 0; reg < 4; reg++) {
                    const int brow = mt * 32 + fm * 16 + lq * 4 + reg;
                    if (brow < Bc) {
                        const size_t oidx = obase + (size_t)(b_off + brow) * 8192;
                        if (isbf) ((__hip_bfloat16*)out)[oidx] =
                            __float2bfloat16(acc4[fm][n2][reg]);
                        else ((float*)out)[oidx] = acc4[fm][n2][reg];
                    }
                }
            }
        }
    }
}

// ---------------------------------------------------------------------------
extern "C" void kernel_launch(void* const* d_in, const int* in_sizes, int n_in,
                              void* d_out, int out_size, void* d_ws, size_t ws_size,
                              hipStream_t stream)
{
    (void)in_sizes; (void)n_in; (void)out_size;

    const void* in_data = d_in[0];
    const void* filt    = d_in[1];
    const void* bias0   = d_in[2];
    const void* fl[7];
    const void* bl[7];
    for (int l = 1; l <= 6; l++) {
        fl[l] = d_in[1 + 2 * l];
        bl[l] = d_in[2 + 2 * l];
    }
    const void* Wd = d_in[15];

    const int Bfull = 128;
    const size_t perB = (size_t)64 * 64 * 64;

    const size_t wbufBytes  = 565248ull * 16;
    const size_t wdbufBytes = 65536ull * 16;
    const size_t bbufBytes  = 17664ull * 4;
    const size_t headBytes  = 256 + wbufBytes + wdbufBytes + bbufBytes;

    const size_t avail = ws_size > headBytes ? ws_size - headBytes : 0;
    int Bc = 0;
    for (int c = 128; c >= 1; c >>= 1) {
        if ((size_t)2 * c * perB * sizeof(__hip_bfloat16) <= avail) { Bc = c; break; }
    }
    if (Bc == 0) return;

    int* flag = (int*)d_ws;
    ushort_t* wbuf  = (ushort_t*)((char*)d_ws + 256);
    ushort_t* wdbuf = (ushort_t*)((char*)d_ws + 256 + wbufBytes);
    float* bbuf = (float*)((char*)d_ws + 256 + wbufBytes + wdbufBytes);
    __hip_bfloat16* bufA = (__hip_bfloat16*)((char*)d_ws + headBytes);
    __hip_bfloat16* bufB = bufA + (size_t)Bc * perB;

    static const size_t w_off[7] = {0, 0, 65536, 327680, 1376256, 2424832, 3473408};
    static const int    b_off_tab[7] = {0, 0, 256, 1280, 5376, 9472, 13568};

    k_prep<<<dim3(2533), 256, 0, stream>>>(
        (const uint32_t*)in_data,
        fl[1], fl[2], fl[3], fl[4], fl[5], fl[6], Wd,
        bl[1], bl[2], bl[3], bl[4], bl[5], bl[6],
        wbuf, wdbuf, bbuf, flag);

    const int mt4 = (Bc + 63) / 64;
    const int mt32 = (Bc + 31) / 32;

    for (int b_off = 0; b_off < Bfull; b_off += Bc) {
        k_stage0<<<dim3(Bc * 64), 256, 0, stream>>>(in_data, filt, bias0, bufA, flag, b_off);

        __hip_bfloat16* cur = bufA;
        __hip_bfloat16* nxt = bufB;
        for (int lvl = 1; lvl <= 3; lvl++) {
            const int Nu = 1 << lvl;
            const int H  = 64 >> lvl;
            const int Nv_in = Nu >> 1;
            dim3 grid(Nv_in * Nv_in * H * H * mt4);
            k_level4<<<grid, 256, 0, stream>>>(cur, wbuf + w_off[lvl],
                bbuf + b_off_tab[lvl], nxt, Nu, H, Bc, mt4);
            __hip_bfloat16* tmp = cur; cur = nxt; nxt = tmp;
        }

        k_f456<<<dim3(64 * mt32), 256, 0, stream>>>(cur,
            wbuf + w_off[4], wbuf + w_off[5], wbuf + w_off[6], wdbuf,
            bbuf + b_off_tab[4], bbuf + b_off_tab[5], bbuf + b_off_tab[6],
            d_out, flag, Bc, b_off, mt32);
    }
}